// Round 10
// baseline (429.593 us; speedup 1.0000x reference)
//
#include <hip/hip_runtime.h>
#include <hip/hip_bf16.h>
#include <math.h>

#define EMB 64
#define HEADS 4
#define HC 256
#define EDGE_DIM 16
#define NEG_SLOPE 0.2f
#define LN_EPS 1e-5f
#define NCOLS 272   // 256 xw cols + 4 a_src + 4 a_dst + 8 pad

typedef __attribute__((ext_vector_type(8))) short short8;
typedef __attribute__((ext_vector_type(4))) float f32x4;

__device__ __forceinline__ float bflo(unsigned int u) { return __uint_as_float(u << 16); }
__device__ __forceinline__ float bfhi(unsigned int u) { return __uint_as_float(u & 0xffff0000u); }
__device__ __forceinline__ float bfu(unsigned short u) { return __uint_as_float((unsigned int)u << 16); }
__device__ __forceinline__ unsigned short bfb(float f) {
    __hip_bfloat16 h = __float2bfloat16(f);
    return *(unsigned short*)&h;
}
__device__ __forceinline__ unsigned int pack_bf2(float a, float b) {
    return (unsigned int)bfb(a) | ((unsigned int)bfb(b) << 16);
}

// prep: zero cnt + dhist; we_att; WpT[64][256] bf16; WxT[272][64] bf16
__global__ void k_prep(const float* __restrict__ W_edge, const float* __restrict__ att_edge,
                       float* __restrict__ we_att, const float* __restrict__ Wp,
                       unsigned short* __restrict__ WpT, const float* __restrict__ W,
                       const float* __restrict__ att_src, const float* __restrict__ att_dst,
                       unsigned short* __restrict__ WxT, int* __restrict__ cnt,
                       int* __restrict__ dhist, int n) {
    int i = blockIdx.x * blockDim.x + threadIdx.x;
    if (i < n) cnt[i] = 0;
    if (i < 64) dhist[i] = 0;
    if (i < EDGE_DIM * HEADS) {
        int d = i >> 2, h = i & 3;
        float acc = 0.0f;
#pragma unroll
        for (int c = 0; c < EMB; ++c)
            acc += W_edge[d * HC + h * EMB + c] * att_edge[h * EMB + c];
        we_att[d * HEADS + h] = acc;
    }
    if (i < HC * EMB) {
        int k = i >> 8, jj = i & 255;              // WpT[k][jj] = Wp[jj][k]
        WpT[i] = bfb(Wp[jj * EMB + k]);
    }
    if (i < NCOLS * EMB) {
        int c = i >> 6, k = i & 63;
        float v = 0.0f;
        if (c < HC) {
            v = W[k * HC + c];
        } else if (c < HC + 4) {
            int h = c - HC;
            float s = 0.0f;
#pragma unroll
            for (int j = 0; j < EMB; ++j) s += W[k * HC + h * EMB + j] * att_src[h * EMB + j];
            v = s;
        } else if (c < HC + 8) {
            int h = c - HC - 4;
            float s = 0.0f;
#pragma unroll
            for (int j = 0; j < EMB; ++j) s += W[k * HC + h * EMB + j] * att_dst[h * EMB + j];
            v = s;
        }
        WxT[i] = bfb(v);
    }
}

// ---- MFMA GEMM: [xw | a_src | a_dst] = x @ Wx ; 16 nodes/block, 4 waves ----
__global__ void __launch_bounds__(256)
k_xw_mfma(const float* __restrict__ x, const unsigned short* __restrict__ WxT,
          __hip_bfloat16* __restrict__ xwb, float* __restrict__ a_src,
          float* __restrict__ a_dst, int n) {
    int tid = threadIdx.x, lane = tid & 63, wv = tid >> 6;
    int g = lane >> 4, r16 = lane & 15;
    int mbase = blockIdx.x * 16;
    int row = mbase + r16;
    if (row >= n) row = n - 1;

    const float* xr = x + (size_t)row * EMB;
    short8 A[2];
#pragma unroll
    for (int kk = 0; kk < 2; ++kk) {
        float4 f0 = *(const float4*)(xr + kk * 32 + 8 * g);
        float4 f1 = *(const float4*)(xr + kk * 32 + 8 * g + 4);
        short8 a;
        a[0] = (short)bfb(f0.x); a[1] = (short)bfb(f0.y);
        a[2] = (short)bfb(f0.z); a[3] = (short)bfb(f0.w);
        a[4] = (short)bfb(f1.x); a[5] = (short)bfb(f1.y);
        a[6] = (short)bfb(f1.z); a[7] = (short)bfb(f1.w);
        A[kk] = a;
    }

    for (int t = wv; t <= 16; t += 4) {
        int col = t * 16 + r16;
        const unsigned short* bp = WxT + (size_t)col * EMB + 8 * g;
        short8 B0 = *(const short8*)(bp);
        short8 B1 = *(const short8*)(bp + 32);
        f32x4 acc = {0.f, 0.f, 0.f, 0.f};
        acc = __builtin_amdgcn_mfma_f32_16x16x32_bf16(A[0], B0, acc, 0, 0, 0);
        acc = __builtin_amdgcn_mfma_f32_16x16x32_bf16(A[1], B1, acc, 0, 0, 0);
        if (t < 16) {
#pragma unroll
            for (int r = 0; r < 4; ++r) {
                int node = mbase + 4 * g + r;
                if (node < n) xwb[(size_t)node * HC + col] = __float2bfloat16(acc[r]);
            }
        } else {
#pragma unroll
            for (int r = 0; r < 4; ++r) {
                int node = mbase + 4 * g + r;
                if (node < n) {
                    if (r16 < 4) a_src[node * HEADS + r16] = acc[r];
                    else if (r16 < 8) a_dst[node * HEADS + r16 - 4] = acc[r];
                }
            }
        }
    }
}

// ---- hist: rank atomic only ----
__global__ void k_hist(const int* __restrict__ ei, int* __restrict__ cnt,
                       int* __restrict__ rank, int E) {
    int e = blockIdx.x * blockDim.x + threadIdx.x;
    if (e < E) rank[e] = atomicAdd(&cnt[ei[E + e]], 1);
}

// ---------------- 3-dispatch exclusive scan over cnt[n] ----------------
__global__ void k_scan1(const int* __restrict__ cnt, int* __restrict__ tmp,
                        int* __restrict__ bsum, int n) {
    __shared__ int s[256];
    int i = blockIdx.x * 256 + threadIdx.x;
    int v = (i < n) ? cnt[i] : 0;
    s[threadIdx.x] = v;
    __syncthreads();
    for (int off = 1; off < 256; off <<= 1) {
        int t = (threadIdx.x >= off) ? s[threadIdx.x - off] : 0;
        __syncthreads();
        s[threadIdx.x] += t;
        __syncthreads();
    }
    if (i < n) tmp[i] = s[threadIdx.x];
    if (threadIdx.x == 255) bsum[blockIdx.x] = s[255];
}

__global__ void k_scan2(int* __restrict__ bsum, int nb) {
    __shared__ int s[256];
    int v = (threadIdx.x < nb) ? bsum[threadIdx.x] : 0;
    s[threadIdx.x] = v;
    __syncthreads();
    for (int off = 1; off < 256; off <<= 1) {
        int t = (threadIdx.x >= off) ? s[threadIdx.x - off] : 0;
        __syncthreads();
        s[threadIdx.x] += t;
        __syncthreads();
    }
    if (threadIdx.x < nb) bsum[threadIdx.x] = s[threadIdx.x] - v; // exclusive
}

__global__ void k_scan3(const int* __restrict__ tmp, const int* __restrict__ cnt,
                        const int* __restrict__ bsum, int* __restrict__ row_start, int n) {
    int i = blockIdx.x * 256 + threadIdx.x;
    if (i < n) row_start[i] = tmp[i] - cnt[i] + bsum[blockIdx.x];
}

// ---------------- degree sort: 64-bin counting sort, descending ----------------
__global__ void k_dhist(const int* __restrict__ cnt, int* __restrict__ dhist, int n) {
    int i = blockIdx.x * blockDim.x + threadIdx.x;
    if (i < n) atomicAdd(&dhist[63 - min(cnt[i], 63)], 1);
}

__global__ void k_dscan(int* __restrict__ dhist) {
    int lane = threadIdx.x & 63;
    int v = dhist[lane];
    int s = v;
#pragma unroll
    for (int off = 1; off < 64; off <<= 1) {
        int t = __shfl_up(s, off);
        if (lane >= off) s += t;
    }
    dhist[lane] = s - v;   // exclusive base
}

__global__ void k_dperm(const int* __restrict__ cnt, int* __restrict__ dhist,
                        int* __restrict__ perm, int n) {
    int i = blockIdx.x * blockDim.x + threadIdx.x;
    if (i < n) {
        int slot = atomicAdd(&dhist[63 - min(cnt[i], 63)], 1);
        perm[slot] = i;
    }
}

// ---- scatter: alpha math + 16B CSR record write (no atomics) ----
// record = { ea01.bf16x2, ea23.bf16x2, src.u32, ae.int8x4 (scale 1/32) }
__global__ void k_scatter(const int* __restrict__ ei, const float* __restrict__ edge_attr,
                          const float* __restrict__ we_att, const float* __restrict__ a_src,
                          const float* __restrict__ a_dst, const int* __restrict__ row_start,
                          const int* __restrict__ rank, uint4* __restrict__ recp, int E) {
    __shared__ float wa[EDGE_DIM * HEADS];
    if (threadIdx.x < EDGE_DIM * HEADS) wa[threadIdx.x] = we_att[threadIdx.x];
    __syncthreads();
    int e = blockIdx.x * blockDim.x + threadIdx.x;
    if (e >= E) return;
    int s = ei[e], d = ei[E + e];
    const float4* ea4 = (const float4*)(edge_attr + (size_t)e * EDGE_DIM);
    float ae[HEADS] = {0.f, 0.f, 0.f, 0.f};
#pragma unroll
    for (int q = 0; q < 4; ++q) {
        float4 v4 = ea4[q];
        const float* vp = (const float*)&v4;
#pragma unroll
        for (int r = 0; r < 4; ++r) {
            float v = vp[r];
            int dd = q * 4 + r;
#pragma unroll
            for (int h = 0; h < HEADS; ++h) ae[h] += v * wa[dd * HEADS + h];
        }
    }
    float4 as4 = *(const float4*)(a_src + (size_t)s * HEADS);
    float4 ad4 = *(const float4*)(a_dst + (size_t)d * HEADS);
    const float* asp = (const float*)&as4;
    const float* adp = (const float*)&ad4;
    float ea[HEADS];
    unsigned int aeq = 0;
#pragma unroll
    for (int h = 0; h < HEADS; ++h) {
        float al = asp[h] + adp[h] + ae[h];
        al = al >= 0.0f ? al : NEG_SLOPE * al;
        ea[h] = __expf(al);          // no max-subtraction needed: |al| < ~8
        int q = __float2int_rn(ae[h] * 32.0f);
        q = max(-127, min(127, q));
        aeq |= ((unsigned int)(q & 0xff)) << (8 * h);
    }
    int pos = row_start[d] + rank[e];
    uint4 w;
    w.x = pack_bf2(ea[0], ea[1]);
    w.y = pack_bf2(ea[2], ea[3]);
    w.z = (unsigned int)s;
    w.w = aeq;
    recp[pos] = w;
}

// ------- fused gather + softmax + aggregate + MFMA proj + LN -------
// 256 threads: 4 degree-matched nodes/block (via perm), 1 wave/node,
// wave-private LDS record staging (no block barriers in gather loop)
__global__ void __launch_bounds__(256)
k_gather_out(const int* __restrict__ row_start, const int* __restrict__ cnt,
             const int* __restrict__ perm, const uint4* __restrict__ recp,
             const float* __restrict__ a_src, const float* __restrict__ a_dst,
             const __hip_bfloat16* __restrict__ xwb, const float* __restrict__ x,
             const float* __restrict__ bias, const unsigned short* __restrict__ WpT,
             const float* __restrict__ bp, const float* __restrict__ gamma,
             const float* __restrict__ beta, float* __restrict__ out, int n) {
    int tid = threadIdx.x, lane = tid & 63, wv = tid >> 6;
    int slot = blockIdx.x * 4 + wv;
    bool valid = slot < n;
    int node = perm[valid ? slot : n - 1];
    int h4 = lane >> 4;
    bool hodd = (h4 & 1);
    int sh1 = (3 - h4) * 8;

    __shared__ __align__(16) uint4 recs[4][64];
    __shared__ __align__(16) unsigned short gbf[4][272];
    __shared__ float pC[4][66];

    const unsigned short* xwu = (const unsigned short*)xwb;

    int rs = row_start[node];
    int dg = valid ? cnt[node] : 0;

    // hoisted self-node loads
    float as = a_src[node * HEADS + h4];
    float ad = a_dst[node * HEADS + h4];
    ushort4 sr = *(const ushort4*)(xwu + (size_t)node * HC + (lane << 2));
    float4 bv = *(const float4*)(bias + (lane << 2));

    float acc0 = 0.f, acc1 = 0.f, acc2 = 0.f, acc3 = 0.f;
    float dn = 0.f, aeS = 0.f;

    for (int base = 0; base < dg; base += 64) {
        int c = min(64, dg - base);
        if (lane < c) recs[wv][lane] = recp[rs + base + lane];
        asm volatile("" ::: "memory");   // wave-synchronous: stage before broadcast reads
        int j = 0;
        for (; j + 8 <= c; j += 8) {
            float av[8]; int sv[8]; float aev[8];
#pragma unroll
            for (int u = 0; u < 8; ++u) {
                uint4 W = recs[wv][j + u];
                unsigned sel = (h4 & 2) ? W.y : W.x;
                av[u] = hodd ? bfhi(sel) : bflo(sel);
                sv[u] = (int)W.z;
                aev[u] = (float)((int)(W.w << sh1) >> 24);
            }
            ushort4 rv[8];
#pragma unroll
            for (int u = 0; u < 8; ++u)
                rv[u] = *(const ushort4*)(xwu + (size_t)sv[u] * HC + (lane << 2));
#pragma unroll
            for (int u = 0; u < 8; ++u) {
                float a = av[u];
                dn += a; aeS += aev[u];
                acc0 += a * bfu(rv[u].x); acc1 += a * bfu(rv[u].y);
                acc2 += a * bfu(rv[u].z); acc3 += a * bfu(rv[u].w);
            }
        }
        for (; j < c; ++j) {
            uint4 W = recs[wv][j];
            unsigned sel = (h4 & 2) ? W.y : W.x;
            float a = hodd ? bfhi(sel) : bflo(sel);
            float ae = (float)((int)(W.w << sh1) >> 24);
            ushort4 r = *(const ushort4*)(xwu + (size_t)W.z * HC + (lane << 2));
            dn += a; aeS += ae;
            acc0 += a * bfu(r.x); acc1 += a * bfu(r.y);
            acc2 += a * bfu(r.z); acc3 += a * bfu(r.w);
        }
        asm volatile("" ::: "memory");   // finish reads before next-chunk restage
    }

    // self-loop + normalize + bias -> bf16 g in LDS
    float cf = fmaxf((float)dg, 1.0f);
    float al = as + ad + (aeS * (1.0f / 32.0f)) / cf;
    al = al >= 0.f ? al : NEG_SLOPE * al;
    float el = __expf(al);
    float inv = 1.0f / (dn + el);
    ushort4 gv;
    gv.x = bfb((acc0 + el * bfu(sr.x)) * inv + bv.x);
    gv.y = bfb((acc1 + el * bfu(sr.y)) * inv + bv.y);
    gv.z = bfb((acc2 + el * bfu(sr.z)) * inv + bv.z);
    gv.w = bfb((acc3 + el * bfu(sr.w)) * inv + bv.w);
    *(ushort4*)&gbf[wv][lane << 2] = gv;
    __syncthreads();

    // MFMA projection: wave wv computes col tile wv (16 cols) of g(4x256) @ Wp(256x64)
    {
        int g = lane >> 4, r16 = lane & 15;
        const unsigned short* wp = WpT + (size_t)(wv * 16 + r16) * HC + 8 * g;
        const unsigned short* ga = &gbf[r16 & 3][8 * g];
        f32x4 pacc = {0.f, 0.f, 0.f, 0.f};
#pragma unroll
        for (int kk = 0; kk < 8; ++kk) {
            short8 Af = *(const short8*)(ga + kk * 32);
            short8 Bf = *(const short8*)(wp + kk * 32);
            pacc = __builtin_amdgcn_mfma_f32_16x16x32_bf16(Af, Bf, pacc, 0, 0, 0);
        }
        if (g == 0) {
#pragma unroll
            for (int m = 0; m < 4; ++m) pC[m][wv * 16 + r16] = pacc[m];
        }
    }
    __syncthreads();

    // epilogue: wave wv -> its node; lane = channel
    float p = pC[wv][lane] + bp[lane];
    float elv = p > 0.f ? p : expm1f(p);
    float xv = valid ? x[(size_t)node * EMB + lane] : 0.f;
    float hv = xv + elv;
    float s1 = hv, s2 = hv * hv;
    for (int off = 32; off > 0; off >>= 1) {
        s1 += __shfl_xor(s1, off);
        s2 += __shfl_xor(s2, off);
    }
    float mu = s1 * (1.0f / EMB);
    float var = s2 * (1.0f / EMB) - mu * mu;
    if (valid)
        out[(size_t)node * EMB + lane] = (hv - mu) * rsqrtf(var + LN_EPS) * gamma[lane] + beta[lane];
}

extern "C" void kernel_launch(void* const* d_in, const int* in_sizes, int n_in,
                              void* d_out, int out_size, void* d_ws, size_t ws_size,
                              hipStream_t stream) {
    const float* x        = (const float*)d_in[0];
    const int*   ei       = (const int*)d_in[1];
    const float* edge_attr= (const float*)d_in[2];
    const float* W        = (const float*)d_in[3];
    const float* W_edge   = (const float*)d_in[4];
    const float* att_src  = (const float*)d_in[5];
    const float* att_dst  = (const float*)d_in[6];
    const float* att_edge = (const float*)d_in[7];
    const float* bias     = (const float*)d_in[8];
    const float* Wp       = (const float*)d_in[9];
    const float* bp       = (const float*)d_in[10];
    const float* gamma    = (const float*)d_in[11];
    const float* beta     = (const float*)d_in[12];
    float* out = (float*)d_out;

    int n = in_sizes[0] / EMB;
    int E = in_sizes[1] / 2;
    int nb = (n + 255) / 256;

    float* ws = (float*)d_ws;
    float* a_src       = ws; ws += (size_t)n * HEADS;
    float* a_dst       = ws; ws += (size_t)n * HEADS;
    float* we_att      = ws; ws += EDGE_DIM * HEADS;
    __hip_bfloat16* xwb = (__hip_bfloat16*)ws; ws += (size_t)n * HC / 2;
    uint4* recp        = (uint4*)ws; ws += (size_t)E * 4;    // 16B/edge
    unsigned short* WpT = (unsigned short*)ws; ws += HC * EMB / 2;
    unsigned short* WxT = (unsigned short*)ws; ws += NCOLS * EMB / 2;
    int* iw = (int*)ws;
    int* cnt       = iw; iw += n;
    int* rank      = iw; iw += E;
    int* row_start = iw; iw += n;
    int* tmp       = iw; iw += n;
    int* bsum      = iw; iw += 256;
    int* dhist     = iw; iw += 64;
    int* perm      = iw; iw += n;

    const int tb = 256;
    hipLaunchKernelGGL(k_prep, dim3((n + tb - 1) / tb), dim3(tb), 0, stream,
                       W_edge, att_edge, we_att, Wp, WpT, W, att_src, att_dst, WxT,
                       cnt, dhist, n);
    hipLaunchKernelGGL(k_xw_mfma, dim3((n + 15) / 16), dim3(tb), 0, stream,
                       x, WxT, xwb, a_src, a_dst, n);
    hipLaunchKernelGGL(k_hist, dim3((E + tb - 1) / tb), dim3(tb), 0, stream, ei, cnt, rank, E);
    hipLaunchKernelGGL(k_scan1, dim3(nb), dim3(tb), 0, stream, cnt, tmp, bsum, n);
    hipLaunchKernelGGL(k_scan2, dim3(1), dim3(tb), 0, stream, bsum, nb);
    hipLaunchKernelGGL(k_scan3, dim3(nb), dim3(tb), 0, stream, tmp, cnt, bsum, row_start, n);
    hipLaunchKernelGGL(k_dhist, dim3((n + tb - 1) / tb), dim3(tb), 0, stream, cnt, dhist, n);
    hipLaunchKernelGGL(k_dscan, dim3(1), dim3(64), 0, stream, dhist);
    hipLaunchKernelGGL(k_dperm, dim3((n + tb - 1) / tb), dim3(tb), 0, stream,
                       cnt, dhist, perm, n);
    hipLaunchKernelGGL(k_scatter, dim3((E + tb - 1) / tb), dim3(tb), 0, stream,
                       ei, edge_attr, we_att, a_src, a_dst, row_start, rank, recp, E);
    hipLaunchKernelGGL(k_gather_out, dim3((n + 3) / 4), dim3(tb), 0, stream,
                       row_start, cnt, perm, recp, a_src, a_dst, xwb, x, bias, WpT, bp,
                       gamma, beta, out, n);
}

// Round 11
// 189.662 us; speedup vs baseline: 2.2650x; 2.2650x over previous
//
#include <hip/hip_runtime.h>
#include <hip/hip_bf16.h>
#include <math.h>

#define EMB 64
#define HEADS 4
#define HC 256
#define EDGE_DIM 16
#define NEG_SLOPE 0.2f
#define LN_EPS 1e-5f
#define NCOLS 272   // 256 xw cols + 4 a_src + 4 a_dst + 8 pad
#define CAP 256     // records staged in LDS per chunk

typedef __attribute__((ext_vector_type(8))) short short8;
typedef __attribute__((ext_vector_type(4))) float f32x4;

__device__ __forceinline__ float bflo(unsigned int u) { return __uint_as_float(u << 16); }
__device__ __forceinline__ float bfhi(unsigned int u) { return __uint_as_float(u & 0xffff0000u); }
__device__ __forceinline__ float bfu(unsigned short u) { return __uint_as_float((unsigned int)u << 16); }
__device__ __forceinline__ unsigned short bfb(float f) {
    __hip_bfloat16 h = __float2bfloat16(f);
    return *(unsigned short*)&h;
}
__device__ __forceinline__ unsigned int pack_bf2(float a, float b) {
    return (unsigned int)bfb(a) | ((unsigned int)bfb(b) << 16);
}

// prep: zero cnt; we_att; WpT[64][256] bf16 (transposed Wp); WxT[272][64] bf16
__global__ void k_prep(const float* __restrict__ W_edge, const float* __restrict__ att_edge,
                       float* __restrict__ we_att, const float* __restrict__ Wp,
                       unsigned short* __restrict__ WpT, const float* __restrict__ W,
                       const float* __restrict__ att_src, const float* __restrict__ att_dst,
                       unsigned short* __restrict__ WxT, int* __restrict__ cnt, int n) {
    int i = blockIdx.x * blockDim.x + threadIdx.x;
    if (i < n) cnt[i] = 0;
    if (i < EDGE_DIM * HEADS) {
        int d = i >> 2, h = i & 3;
        float acc = 0.0f;
#pragma unroll
        for (int c = 0; c < EMB; ++c)
            acc += W_edge[d * HC + h * EMB + c] * att_edge[h * EMB + c];
        we_att[d * HEADS + h] = acc;
    }
    if (i < HC * EMB) {
        int k = i >> 8, jj = i & 255;              // WpT[k][jj] = Wp[jj][k]
        WpT[i] = bfb(Wp[jj * EMB + k]);
    }
    if (i < NCOLS * EMB) {
        int c = i >> 6, k = i & 63;
        float v = 0.0f;
        if (c < HC) {
            v = W[k * HC + c];
        } else if (c < HC + 4) {
            int h = c - HC;
            float s = 0.0f;
#pragma unroll
            for (int j = 0; j < EMB; ++j) s += W[k * HC + h * EMB + j] * att_src[h * EMB + j];
            v = s;
        } else if (c < HC + 8) {
            int h = c - HC - 4;
            float s = 0.0f;
#pragma unroll
            for (int j = 0; j < EMB; ++j) s += W[k * HC + h * EMB + j] * att_dst[h * EMB + j];
            v = s;
        }
        WxT[i] = bfb(v);
    }
}

// ---- MFMA GEMM: [xw | a_src | a_dst] = x @ Wx ; 16 nodes/block, 4 waves ----
// fused tail: dst-histogram rank atomic (one edge per thread, grid-stride)
__global__ void __launch_bounds__(256)
k_xw_mfma(const float* __restrict__ x, const unsigned short* __restrict__ WxT,
          __hip_bfloat16* __restrict__ xwb, float* __restrict__ a_src,
          float* __restrict__ a_dst, int n,
          const int* __restrict__ ei, int* __restrict__ cnt,
          int* __restrict__ rank, int E) {
    int tid = threadIdx.x, lane = tid & 63, wv = tid >> 6;
    int g = lane >> 4, r16 = lane & 15;
    int mbase = blockIdx.x * 16;
    int row = mbase + r16;
    if (row >= n) row = n - 1;

    const float* xr = x + (size_t)row * EMB;
    short8 A[2];
#pragma unroll
    for (int kk = 0; kk < 2; ++kk) {
        float4 f0 = *(const float4*)(xr + kk * 32 + 8 * g);
        float4 f1 = *(const float4*)(xr + kk * 32 + 8 * g + 4);
        short8 a;
        a[0] = (short)bfb(f0.x); a[1] = (short)bfb(f0.y);
        a[2] = (short)bfb(f0.z); a[3] = (short)bfb(f0.w);
        a[4] = (short)bfb(f1.x); a[5] = (short)bfb(f1.y);
        a[6] = (short)bfb(f1.z); a[7] = (short)bfb(f1.w);
        A[kk] = a;
    }

    for (int t = wv; t <= 16; t += 4) {
        int col = t * 16 + r16;
        const unsigned short* bp = WxT + (size_t)col * EMB + 8 * g;
        short8 B0 = *(const short8*)(bp);
        short8 B1 = *(const short8*)(bp + 32);
        f32x4 acc = {0.f, 0.f, 0.f, 0.f};
        acc = __builtin_amdgcn_mfma_f32_16x16x32_bf16(A[0], B0, acc, 0, 0, 0);
        acc = __builtin_amdgcn_mfma_f32_16x16x32_bf16(A[1], B1, acc, 0, 0, 0);
        if (t < 16) {
#pragma unroll
            for (int r = 0; r < 4; ++r) {
                int node = mbase + 4 * g + r;
                if (node < n) xwb[(size_t)node * HC + col] = __float2bfloat16(acc[r]);
            }
        } else {
#pragma unroll
            for (int r = 0; r < 4; ++r) {
                int node = mbase + 4 * g + r;
                if (node < n) {
                    if (r16 < 4) a_src[node * HEADS + r16] = acc[r];
                    else if (r16 < 8) a_dst[node * HEADS + r16 - 4] = acc[r];
                }
            }
        }
    }

    // fused histogram: rank of each edge within its dst bucket
    int stride = gridDim.x * blockDim.x;
    for (int e = blockIdx.x * blockDim.x + tid; e < E; e += stride)
        rank[e] = atomicAdd(&cnt[ei[E + e]], 1);
}

// ---------------- 3-dispatch exclusive scan over cnt[n] ----------------
__global__ void k_scan1(const int* __restrict__ cnt, int* __restrict__ tmp,
                        int* __restrict__ bsum, int n) {
    __shared__ int s[256];
    int i = blockIdx.x * 256 + threadIdx.x;
    int v = (i < n) ? cnt[i] : 0;
    s[threadIdx.x] = v;
    __syncthreads();
    for (int off = 1; off < 256; off <<= 1) {
        int t = (threadIdx.x >= off) ? s[threadIdx.x - off] : 0;
        __syncthreads();
        s[threadIdx.x] += t;
        __syncthreads();
    }
    if (i < n) tmp[i] = s[threadIdx.x];
    if (threadIdx.x == 255) bsum[blockIdx.x] = s[255];
}

__global__ void k_scan2(int* __restrict__ bsum, int nb) {
    __shared__ int s[256];
    int v = (threadIdx.x < nb) ? bsum[threadIdx.x] : 0;
    s[threadIdx.x] = v;
    __syncthreads();
    for (int off = 1; off < 256; off <<= 1) {
        int t = (threadIdx.x >= off) ? s[threadIdx.x - off] : 0;
        __syncthreads();
        s[threadIdx.x] += t;
        __syncthreads();
    }
    if (threadIdx.x < nb) bsum[threadIdx.x] = s[threadIdx.x] - v; // exclusive
}

__global__ void k_scan3(const int* __restrict__ tmp, const int* __restrict__ cnt,
                        const int* __restrict__ bsum, int* __restrict__ row_start, int n) {
    int i = blockIdx.x * 256 + threadIdx.x;
    if (i < n) row_start[i] = tmp[i] - cnt[i] + bsum[blockIdx.x];
}

// ---- scatter: alpha math + 16B CSR record write (no atomics) ----
// record = { ea01.bf16x2, ea23.bf16x2, src.u32, ae.int8x4 (scale 1/32) }
__global__ void k_scatter(const int* __restrict__ ei, const float* __restrict__ edge_attr,
                          const float* __restrict__ we_att, const float* __restrict__ a_src,
                          const float* __restrict__ a_dst, const int* __restrict__ row_start,
                          const int* __restrict__ rank, uint4* __restrict__ recp, int E) {
    __shared__ float wa[EDGE_DIM * HEADS];
    if (threadIdx.x < EDGE_DIM * HEADS) wa[threadIdx.x] = we_att[threadIdx.x];
    __syncthreads();
    int e = blockIdx.x * blockDim.x + threadIdx.x;
    if (e >= E) return;
    int s = ei[e], d = ei[E + e];
    const float4* ea4 = (const float4*)(edge_attr + (size_t)e * EDGE_DIM);
    float ae[HEADS] = {0.f, 0.f, 0.f, 0.f};
#pragma unroll
    for (int q = 0; q < 4; ++q) {
        float4 v4 = ea4[q];
        const float* vp = (const float*)&v4;
#pragma unroll
        for (int r = 0; r < 4; ++r) {
            float v = vp[r];
            int dd = q * 4 + r;
#pragma unroll
            for (int h = 0; h < HEADS; ++h) ae[h] += v * wa[dd * HEADS + h];
        }
    }
    float4 as4 = *(const float4*)(a_src + (size_t)s * HEADS);
    float4 ad4 = *(const float4*)(a_dst + (size_t)d * HEADS);
    const float* asp = (const float*)&as4;
    const float* adp = (const float*)&ad4;
    float ea[HEADS];
    unsigned int aeq = 0;
#pragma unroll
    for (int h = 0; h < HEADS; ++h) {
        float al = asp[h] + adp[h] + ae[h];
        al = al >= 0.0f ? al : NEG_SLOPE * al;
        ea[h] = __expf(al);          // no max-subtraction needed: |al| < ~8
        int q = __float2int_rn(ae[h] * 32.0f);
        q = max(-127, min(127, q));
        aeq |= ((unsigned int)(q & 0xff)) << (8 * h);
    }
    int pos = row_start[d] + rank[e];
    uint4 w;
    w.x = pack_bf2(ea[0], ea[1]);
    w.y = pack_bf2(ea[2], ea[3]);
    w.z = (unsigned int)s;
    w.w = aeq;
    recp[pos] = w;
}

// ------- fused gather (LDS-staged records) + softmax + aggregate + MFMA proj + LN -------
// 256 threads: 4 nodes/block, 1 wave/node
__global__ void __launch_bounds__(256)
k_gather_out(const int* __restrict__ row_start, const int* __restrict__ cnt,
             const uint4* __restrict__ recp,
             const float* __restrict__ a_src, const float* __restrict__ a_dst,
             const __hip_bfloat16* __restrict__ xwb, const float* __restrict__ x,
             const float* __restrict__ bias, const unsigned short* __restrict__ WpT,
             const float* __restrict__ bp, const float* __restrict__ gamma,
             const float* __restrict__ beta, float* __restrict__ out, int n) {
    int tid = threadIdx.x, lane = tid & 63, wv = tid >> 6;
    int node = blockIdx.x * 4 + wv;
    bool valid = node < n;
    int nodeC = valid ? node : n - 1;
    int h4 = lane >> 4;
    bool hodd = (h4 & 1);
    int sh1 = (3 - h4) * 8;

    __shared__ __align__(16) uint4 recs[CAP];
    __shared__ __align__(16) unsigned short gbf[4][272];
    __shared__ float pC[4][66];

    const unsigned short* xwu = (const unsigned short*)xwb;

    // block's contiguous record range
    int first = blockIdx.x * 4;
    int last = min(first + 4, n) - 1;
    int rs0 = row_start[first];
    int total = row_start[last] + cnt[last] - rs0;

    int dg = valid ? cnt[nodeC] : 0;
    int myLo = row_start[nodeC] - rs0;
    int myHi = myLo + dg;

    // hoisted self-node loads
    float as = a_src[nodeC * HEADS + h4];
    float ad = a_dst[nodeC * HEADS + h4];
    ushort4 sr = *(const ushort4*)(xwu + (size_t)nodeC * HC + (lane << 2));
    float4 bv = *(const float4*)(bias + (lane << 2));

    float acc0 = 0.f, acc1 = 0.f, acc2 = 0.f, acc3 = 0.f;
    float dn = 0.f, aeS = 0.f;

    for (int base = 0; base < total; base += CAP) {
        int cend = min(total, base + CAP);
        if (base) __syncthreads();
        for (int idx = base + tid; idx < cend; idx += 256)
            recs[idx - base] = recp[rs0 + idx];
        __syncthreads();
        int lo = max(myLo, base), hi = min(myHi, cend);
        int c = hi - lo;
        int o = lo - base;
        int j = 0;
        for (; j + 8 <= c; j += 8) {
            float av[8]; int sv[8]; float aev[8];
#pragma unroll
            for (int u = 0; u < 8; ++u) {
                uint4 W = recs[o + j + u];
                unsigned sel = (h4 & 2) ? W.y : W.x;
                av[u] = hodd ? bfhi(sel) : bflo(sel);
                sv[u] = (int)W.z;
                aev[u] = (float)((int)(W.w << sh1) >> 24);
            }
            ushort4 rv[8];
#pragma unroll
            for (int u = 0; u < 8; ++u)
                rv[u] = *(const ushort4*)(xwu + (size_t)sv[u] * HC + (lane << 2));
#pragma unroll
            for (int u = 0; u < 8; ++u) {
                float a = av[u];
                dn += a; aeS += aev[u];
                acc0 += a * bfu(rv[u].x); acc1 += a * bfu(rv[u].y);
                acc2 += a * bfu(rv[u].z); acc3 += a * bfu(rv[u].w);
            }
        }
        for (; j < c; ++j) {
            uint4 W = recs[o + j];
            unsigned sel = (h4 & 2) ? W.y : W.x;
            float a = hodd ? bfhi(sel) : bflo(sel);
            float ae = (float)((int)(W.w << sh1) >> 24);
            ushort4 r = *(const ushort4*)(xwu + (size_t)W.z * HC + (lane << 2));
            dn += a; aeS += ae;
            acc0 += a * bfu(r.x); acc1 += a * bfu(r.y);
            acc2 += a * bfu(r.z); acc3 += a * bfu(r.w);
        }
    }

    // self-loop + normalize + bias -> bf16 g in LDS
    float cf = fmaxf((float)dg, 1.0f);
    float al = as + ad + (aeS * (1.0f / 32.0f)) / cf;
    al = al >= 0.f ? al : NEG_SLOPE * al;
    float el = __expf(al);
    float inv = 1.0f / (dn + el);
    ushort4 gv;
    gv.x = bfb((acc0 + el * bfu(sr.x)) * inv + bv.x);
    gv.y = bfb((acc1 + el * bfu(sr.y)) * inv + bv.y);
    gv.z = bfb((acc2 + el * bfu(sr.z)) * inv + bv.z);
    gv.w = bfb((acc3 + el * bfu(sr.w)) * inv + bv.w);
    *(ushort4*)&gbf[wv][lane << 2] = gv;
    __syncthreads();

    // MFMA projection: wave wv computes col tile wv (16 cols) of g(4x256) @ Wp(256x64)
    {
        int g = lane >> 4, r16 = lane & 15;
        const unsigned short* wp = WpT + (size_t)(wv * 16 + r16) * HC + 8 * g;
        const unsigned short* ga = &gbf[r16 & 3][8 * g];
        f32x4 pacc = {0.f, 0.f, 0.f, 0.f};
#pragma unroll
        for (int kk = 0; kk < 8; ++kk) {
            short8 Af = *(const short8*)(ga + kk * 32);
            short8 Bf = *(const short8*)(wp + kk * 32);
            pacc = __builtin_amdgcn_mfma_f32_16x16x32_bf16(Af, Bf, pacc, 0, 0, 0);
        }
        if (g == 0) {
#pragma unroll
            for (int m = 0; m < 4; ++m) pC[m][wv * 16 + r16] = pacc[m];
        }
    }
    __syncthreads();

    // epilogue: wave wv -> node wv; lane = channel
    float p = pC[wv][lane] + bp[lane];
    float elv = p > 0.f ? p : expm1f(p);
    float xv = valid ? x[(size_t)node * EMB + lane] : 0.f;
    float hv = xv + elv;
    float s1 = hv, s2 = hv * hv;
    for (int off = 32; off > 0; off >>= 1) {
        s1 += __shfl_xor(s1, off);
        s2 += __shfl_xor(s2, off);
    }
    float mu = s1 * (1.0f / EMB);
    float var = s2 * (1.0f / EMB) - mu * mu;
    if (valid)
        out[(size_t)node * EMB + lane] = (hv - mu) * rsqrtf(var + LN_EPS) * gamma[lane] + beta[lane];
}

extern "C" void kernel_launch(void* const* d_in, const int* in_sizes, int n_in,
                              void* d_out, int out_size, void* d_ws, size_t ws_size,
                              hipStream_t stream) {
    const float* x        = (const float*)d_in[0];
    const int*   ei       = (const int*)d_in[1];
    const float* edge_attr= (const float*)d_in[2];
    const float* W        = (const float*)d_in[3];
    const float* W_edge   = (const float*)d_in[4];
    const float* att_src  = (const float*)d_in[5];
    const float* att_dst  = (const float*)d_in[6];
    const float* att_edge = (const float*)d_in[7];
    const float* bias     = (const float*)d_in[8];
    const float* Wp       = (const float*)d_in[9];
    const float* bp       = (const float*)d_in[10];
    const float* gamma    = (const float*)d_in[11];
    const float* beta     = (const float*)d_in[12];
    float* out = (float*)d_out;

    int n = in_sizes[0] / EMB;
    int E = in_sizes[1] / 2;
    int nb = (n + 255) / 256;

    float* ws = (float*)d_ws;
    float* a_src       = ws; ws += (size_t)n * HEADS;
    float* a_dst       = ws; ws += (size_t)n * HEADS;
    float* we_att      = ws; ws += EDGE_DIM * HEADS;
    __hip_bfloat16* xwb = (__hip_bfloat16*)ws; ws += (size_t)n * HC / 2;
    uint4* recp        = (uint4*)ws; ws += (size_t)E * 4;    // 16B/edge
    unsigned short* WpT = (unsigned short*)ws; ws += HC * EMB / 2;
    unsigned short* WxT = (unsigned short*)ws; ws += NCOLS * EMB / 2;
    int* iw = (int*)ws;
    int* cnt       = iw; iw += n;
    int* rank      = iw; iw += E;
    int* row_start = iw; iw += n;
    int* tmp       = iw; iw += n;
    int* bsum      = iw; iw += 256;

    const int tb = 256;
    hipLaunchKernelGGL(k_prep, dim3((n + tb - 1) / tb), dim3(tb), 0, stream,
                       W_edge, att_edge, we_att, Wp, WpT, W, att_src, att_dst, WxT, cnt, n);
    hipLaunchKernelGGL(k_xw_mfma, dim3((n + 15) / 16), dim3(tb), 0, stream,
                       x, WxT, xwb, a_src, a_dst, n, ei, cnt, rank, E);
    hipLaunchKernelGGL(k_scan1, dim3(nb), dim3(tb), 0, stream, cnt, tmp, bsum, n);
    hipLaunchKernelGGL(k_scan2, dim3(1), dim3(tb), 0, stream, bsum, nb);
    hipLaunchKernelGGL(k_scan3, dim3(nb), dim3(tb), 0, stream, tmp, cnt, bsum, row_start, n);
    hipLaunchKernelGGL(k_scatter, dim3((E + tb - 1) / tb), dim3(tb), 0, stream,
                       ei, edge_attr, we_att, a_src, a_dst, row_start, rank, recp, E);
    hipLaunchKernelGGL(k_gather_out, dim3((n + 3) / 4), dim3(tb), 0, stream,
                       row_start, cnt, recp, a_src, a_dst, xwb, x, bias, WpT, bp,
                       gamma, beta, out, n);
}

// Round 12
// 187.657 us; speedup vs baseline: 2.2893x; 1.0107x over previous
//
#include <hip/hip_runtime.h>
#include <hip/hip_bf16.h>
#include <hip/hip_fp8.h>
#include <math.h>

#define EMB 64
#define HEADS 4
#define HC 256
#define EDGE_DIM 16
#define NEG_SLOPE 0.2f
#define LN_EPS 1e-5f
#define NCOLS 272   // 256 xw cols + 4 a_src + 4 a_dst + 8 pad
#define CAP 256     // records staged in LDS per chunk

typedef __attribute__((ext_vector_type(8))) short short8;
typedef __attribute__((ext_vector_type(4))) float f32x4;

__device__ __forceinline__ float bflo(unsigned int u) { return __uint_as_float(u << 16); }
__device__ __forceinline__ float bfhi(unsigned int u) { return __uint_as_float(u & 0xffff0000u); }
__device__ __forceinline__ float bfu(unsigned short u) { return __uint_as_float((unsigned int)u << 16); }
__device__ __forceinline__ unsigned short bfb(float f) {
    __hip_bfloat16 h = __float2bfloat16(f);
    return *(unsigned short*)&h;
}
__device__ __forceinline__ unsigned int pack_bf2(float a, float b) {
    return (unsigned int)bfb(a) | ((unsigned int)bfb(b) << 16);
}
__device__ __forceinline__ float fp8tof(unsigned int b) {
    __hip_fp8_e4m3 t; t.__x = (__hip_fp8_storage_t)(b & 0xffu); return (float)t;
}
__device__ __forceinline__ unsigned char ftofp8(float f) {
    __hip_fp8_e4m3 t(f); return (unsigned char)t.__x;
}

// prep: zero cnt; we_att; WpT[64][256] bf16 (transposed Wp); WxT[272][64] bf16
__global__ void k_prep(const float* __restrict__ W_edge, const float* __restrict__ att_edge,
                       float* __restrict__ we_att, const float* __restrict__ Wp,
                       unsigned short* __restrict__ WpT, const float* __restrict__ W,
                       const float* __restrict__ att_src, const float* __restrict__ att_dst,
                       unsigned short* __restrict__ WxT, int* __restrict__ cnt, int n) {
    int i = blockIdx.x * blockDim.x + threadIdx.x;
    if (i < n) cnt[i] = 0;
    if (i < EDGE_DIM * HEADS) {
        int d = i >> 2, h = i & 3;
        float acc = 0.0f;
#pragma unroll
        for (int c = 0; c < EMB; ++c)
            acc += W_edge[d * HC + h * EMB + c] * att_edge[h * EMB + c];
        we_att[d * HEADS + h] = acc;
    }
    if (i < HC * EMB) {
        int k = i >> 8, jj = i & 255;              // WpT[k][jj] = Wp[jj][k]
        WpT[i] = bfb(Wp[jj * EMB + k]);
    }
    if (i < NCOLS * EMB) {
        int c = i >> 6, k = i & 63;
        float v = 0.0f;
        if (c < HC) {
            v = W[k * HC + c];
        } else if (c < HC + 4) {
            int h = c - HC;
            float s = 0.0f;
#pragma unroll
            for (int j = 0; j < EMB; ++j) s += W[k * HC + h * EMB + j] * att_src[h * EMB + j];
            v = s;
        } else if (c < HC + 8) {
            int h = c - HC - 4;
            float s = 0.0f;
#pragma unroll
            for (int j = 0; j < EMB; ++j) s += W[k * HC + h * EMB + j] * att_dst[h * EMB + j];
            v = s;
        }
        WxT[i] = bfb(v);
    }
}

// ---- MFMA GEMM: [xw(fp8) | a_src | a_dst] = x @ Wx ; 16 nodes/block, 4 waves ----
// fused tail: dst-histogram rank atomic (one edge per thread, grid-stride)
__global__ void __launch_bounds__(256)
k_xw_mfma(const float* __restrict__ x, const unsigned short* __restrict__ WxT,
          unsigned char* __restrict__ xwf8, float* __restrict__ a_src,
          float* __restrict__ a_dst, int n,
          const int* __restrict__ ei, int* __restrict__ cnt,
          int* __restrict__ rank, int E) {
    int tid = threadIdx.x, lane = tid & 63, wv = tid >> 6;
    int g = lane >> 4, r16 = lane & 15;
    int mbase = blockIdx.x * 16;
    int row = mbase + r16;
    if (row >= n) row = n - 1;

    const float* xr = x + (size_t)row * EMB;
    short8 A[2];
#pragma unroll
    for (int kk = 0; kk < 2; ++kk) {
        float4 f0 = *(const float4*)(xr + kk * 32 + 8 * g);
        float4 f1 = *(const float4*)(xr + kk * 32 + 8 * g + 4);
        short8 a;
        a[0] = (short)bfb(f0.x); a[1] = (short)bfb(f0.y);
        a[2] = (short)bfb(f0.z); a[3] = (short)bfb(f0.w);
        a[4] = (short)bfb(f1.x); a[5] = (short)bfb(f1.y);
        a[6] = (short)bfb(f1.z); a[7] = (short)bfb(f1.w);
        A[kk] = a;
    }

    for (int t = wv; t <= 16; t += 4) {
        int col = t * 16 + r16;
        const unsigned short* bp = WxT + (size_t)col * EMB + 8 * g;
        short8 B0 = *(const short8*)(bp);
        short8 B1 = *(const short8*)(bp + 32);
        f32x4 acc = {0.f, 0.f, 0.f, 0.f};
        acc = __builtin_amdgcn_mfma_f32_16x16x32_bf16(A[0], B0, acc, 0, 0, 0);
        acc = __builtin_amdgcn_mfma_f32_16x16x32_bf16(A[1], B1, acc, 0, 0, 0);
        if (t < 16) {
#pragma unroll
            for (int r = 0; r < 4; ++r) {
                int node = mbase + 4 * g + r;
                if (node < n) xwf8[(size_t)node * HC + col] = ftofp8(acc[r]);
            }
        } else {
#pragma unroll
            for (int r = 0; r < 4; ++r) {
                int node = mbase + 4 * g + r;
                if (node < n) {
                    if (r16 < 4) a_src[node * HEADS + r16] = acc[r];
                    else if (r16 < 8) a_dst[node * HEADS + r16 - 4] = acc[r];
                }
            }
        }
    }

    // fused histogram: rank of each edge within its dst bucket
    int stride = gridDim.x * blockDim.x;
    for (int e = blockIdx.x * blockDim.x + tid; e < E; e += stride)
        rank[e] = atomicAdd(&cnt[ei[E + e]], 1);
}

// ---------------- 3-dispatch exclusive scan over cnt[n] ----------------
__global__ void k_scan1(const int* __restrict__ cnt, int* __restrict__ tmp,
                        int* __restrict__ bsum, int n) {
    __shared__ int s[256];
    int i = blockIdx.x * 256 + threadIdx.x;
    int v = (i < n) ? cnt[i] : 0;
    s[threadIdx.x] = v;
    __syncthreads();
    for (int off = 1; off < 256; off <<= 1) {
        int t = (threadIdx.x >= off) ? s[threadIdx.x - off] : 0;
        __syncthreads();
        s[threadIdx.x] += t;
        __syncthreads();
    }
    if (i < n) tmp[i] = s[threadIdx.x];
    if (threadIdx.x == 255) bsum[blockIdx.x] = s[255];
}

__global__ void k_scan2(int* __restrict__ bsum, int nb) {
    __shared__ int s[256];
    int v = (threadIdx.x < nb) ? bsum[threadIdx.x] : 0;
    s[threadIdx.x] = v;
    __syncthreads();
    for (int off = 1; off < 256; off <<= 1) {
        int t = (threadIdx.x >= off) ? s[threadIdx.x - off] : 0;
        __syncthreads();
        s[threadIdx.x] += t;
        __syncthreads();
    }
    if (threadIdx.x < nb) bsum[threadIdx.x] = s[threadIdx.x] - v; // exclusive
}

__global__ void k_scan3(const int* __restrict__ tmp, const int* __restrict__ cnt,
                        const int* __restrict__ bsum, int* __restrict__ row_start, int n) {
    int i = blockIdx.x * 256 + threadIdx.x;
    if (i < n) row_start[i] = tmp[i] - cnt[i] + bsum[blockIdx.x];
}

// ---- scatter: alpha math + 16B CSR record write (no atomics) ----
// record = { ea01.bf16x2, ea23.bf16x2, src.u32, ae.int8x4 (scale 1/32) }
__global__ void k_scatter(const int* __restrict__ ei, const float* __restrict__ edge_attr,
                          const float* __restrict__ we_att, const float* __restrict__ a_src,
                          const float* __restrict__ a_dst, const int* __restrict__ row_start,
                          const int* __restrict__ rank, uint4* __restrict__ recp, int E) {
    __shared__ float wa[EDGE_DIM * HEADS];
    if (threadIdx.x < EDGE_DIM * HEADS) wa[threadIdx.x] = we_att[threadIdx.x];
    __syncthreads();
    int e = blockIdx.x * blockDim.x + threadIdx.x;
    if (e >= E) return;
    int s = ei[e], d = ei[E + e];
    const float4* ea4 = (const float4*)(edge_attr + (size_t)e * EDGE_DIM);
    float ae[HEADS] = {0.f, 0.f, 0.f, 0.f};
#pragma unroll
    for (int q = 0; q < 4; ++q) {
        float4 v4 = ea4[q];
        const float* vp = (const float*)&v4;
#pragma unroll
        for (int r = 0; r < 4; ++r) {
            float v = vp[r];
            int dd = q * 4 + r;
#pragma unroll
            for (int h = 0; h < HEADS; ++h) ae[h] += v * wa[dd * HEADS + h];
        }
    }
    float4 as4 = *(const float4*)(a_src + (size_t)s * HEADS);
    float4 ad4 = *(const float4*)(a_dst + (size_t)d * HEADS);
    const float* asp = (const float*)&as4;
    const float* adp = (const float*)&ad4;
    float ea[HEADS];
    unsigned int aeq = 0;
#pragma unroll
    for (int h = 0; h < HEADS; ++h) {
        float al = asp[h] + adp[h] + ae[h];
        al = al >= 0.0f ? al : NEG_SLOPE * al;
        ea[h] = __expf(al);          // no max-subtraction needed: |al| < ~8
        int q = __float2int_rn(ae[h] * 32.0f);
        q = max(-127, min(127, q));
        aeq |= ((unsigned int)(q & 0xff)) << (8 * h);
    }
    int pos = row_start[d] + rank[e];
    uint4 w;
    w.x = pack_bf2(ea[0], ea[1]);
    w.y = pack_bf2(ea[2], ea[3]);
    w.z = (unsigned int)s;
    w.w = aeq;
    recp[pos] = w;
}

// ------- fused gather (LDS-staged records) + softmax + aggregate + MFMA proj + LN -------
// 256 threads: 4 nodes/block, 1 wave/node; xw rows are fp8 e4m3 (256B)
__global__ void __launch_bounds__(256)
k_gather_out(const int* __restrict__ row_start, const int* __restrict__ cnt,
             const uint4* __restrict__ recp,
             const float* __restrict__ a_src, const float* __restrict__ a_dst,
             const unsigned char* __restrict__ xwf8, const float* __restrict__ x,
             const float* __restrict__ bias, const unsigned short* __restrict__ WpT,
             const float* __restrict__ bp, const float* __restrict__ gamma,
             const float* __restrict__ beta, float* __restrict__ out, int n) {
    int tid = threadIdx.x, lane = tid & 63, wv = tid >> 6;
    int node = blockIdx.x * 4 + wv;
    bool valid = node < n;
    int nodeC = valid ? node : n - 1;
    int h4 = lane >> 4;
    bool hodd = (h4 & 1);
    int sh1 = (3 - h4) * 8;

    __shared__ __align__(16) uint4 recs[CAP];
    __shared__ __align__(16) unsigned short gbf[4][272];
    __shared__ float pC[4][66];

    // block's contiguous record range
    int first = blockIdx.x * 4;
    int last = min(first + 4, n) - 1;
    int rs0 = row_start[first];
    int total = row_start[last] + cnt[last] - rs0;

    int dg = valid ? cnt[nodeC] : 0;
    int myLo = row_start[nodeC] - rs0;
    int myHi = myLo + dg;

    // hoisted self-node loads
    float as = a_src[nodeC * HEADS + h4];
    float ad = a_dst[nodeC * HEADS + h4];
    unsigned int sr8 = *(const unsigned int*)(xwf8 + (size_t)nodeC * HC + (lane << 2));
    float4 bv = *(const float4*)(bias + (lane << 2));

    float acc0 = 0.f, acc1 = 0.f, acc2 = 0.f, acc3 = 0.f;
    float dn = 0.f, aeS = 0.f;

    for (int base = 0; base < total; base += CAP) {
        int cend = min(total, base + CAP);
        if (base) __syncthreads();
        for (int idx = base + tid; idx < cend; idx += 256)
            recs[idx - base] = recp[rs0 + idx];
        __syncthreads();
        int lo = max(myLo, base), hi = min(myHi, cend);
        int c = hi - lo;
        int o = lo - base;
        int j = 0;
        for (; j + 8 <= c; j += 8) {
            float av[8]; int sv[8]; float aev[8];
#pragma unroll
            for (int u = 0; u < 8; ++u) {
                uint4 W = recs[o + j + u];
                unsigned sel = (h4 & 2) ? W.y : W.x;
                av[u] = hodd ? bfhi(sel) : bflo(sel);
                sv[u] = (int)W.z;
                aev[u] = (float)((int)(W.w << sh1) >> 24);
            }
            unsigned int rv[8];
#pragma unroll
            for (int u = 0; u < 8; ++u)
                rv[u] = *(const unsigned int*)(xwf8 + (size_t)sv[u] * HC + (lane << 2));
#pragma unroll
            for (int u = 0; u < 8; ++u) {
                float a = av[u];
                dn += a; aeS += aev[u];
                acc0 += a * fp8tof(rv[u]);
                acc1 += a * fp8tof(rv[u] >> 8);
                acc2 += a * fp8tof(rv[u] >> 16);
                acc3 += a * fp8tof(rv[u] >> 24);
            }
        }
        for (; j < c; ++j) {
            uint4 W = recs[o + j];
            unsigned sel = (h4 & 2) ? W.y : W.x;
            float a = hodd ? bfhi(sel) : bflo(sel);
            float ae = (float)((int)(W.w << sh1) >> 24);
            unsigned int rv = *(const unsigned int*)(xwf8 + (size_t)W.z * HC + (lane << 2));
            dn += a; aeS += ae;
            acc0 += a * fp8tof(rv);
            acc1 += a * fp8tof(rv >> 8);
            acc2 += a * fp8tof(rv >> 16);
            acc3 += a * fp8tof(rv >> 24);
        }
    }

    // self-loop + normalize + bias -> bf16 g in LDS
    float cf = fmaxf((float)dg, 1.0f);
    float al = as + ad + (aeS * (1.0f / 32.0f)) / cf;
    al = al >= 0.f ? al : NEG_SLOPE * al;
    float el = __expf(al);
    float inv = 1.0f / (dn + el);
    ushort4 gv;
    gv.x = bfb((acc0 + el * fp8tof(sr8)) * inv + bv.x);
    gv.y = bfb((acc1 + el * fp8tof(sr8 >> 8)) * inv + bv.y);
    gv.z = bfb((acc2 + el * fp8tof(sr8 >> 16)) * inv + bv.z);
    gv.w = bfb((acc3 + el * fp8tof(sr8 >> 24)) * inv + bv.w);
    *(ushort4*)&gbf[wv][lane << 2] = gv;
    __syncthreads();

    // MFMA projection: wave wv computes col tile wv (16 cols) of g(4x256) @ Wp(256x64)
    {
        int g = lane >> 4, r16 = lane & 15;
        const unsigned short* wp = WpT + (size_t)(wv * 16 + r16) * HC + 8 * g;
        const unsigned short* ga = &gbf[r16 & 3][8 * g];
        f32x4 pacc = {0.f, 0.f, 0.f, 0.f};
#pragma unroll
        for (int kk = 0; kk < 8; ++kk) {
            short8 Af = *(const short8*)(ga + kk * 32);
            short8 Bf = *(const short8*)(wp + kk * 32);
            pacc = __builtin_amdgcn_mfma_f32_16x16x32_bf16(Af, Bf, pacc, 0, 0, 0);
        }
        if (g == 0) {
#pragma unroll
            for (int m = 0; m < 4; ++m) pC[m][wv * 16 + r16] = pacc[m];
        }
    }
    __syncthreads();

    // epilogue: wave wv -> node wv; lane = channel
    float p = pC[wv][lane] + bp[lane];
    float elv = p > 0.f ? p : expm1f(p);
    float xv = valid ? x[(size_t)node * EMB + lane] : 0.f;
    float hv = xv + elv;
    float s1 = hv, s2 = hv * hv;
    for (int off = 32; off > 0; off >>= 1) {
        s1 += __shfl_xor(s1, off);
        s2 += __shfl_xor(s2, off);
    }
    float mu = s1 * (1.0f / EMB);
    float var = s2 * (1.0f / EMB) - mu * mu;
    if (valid)
        out[(size_t)node * EMB + lane] = (hv - mu) * rsqrtf(var + LN_EPS) * gamma[lane] + beta[lane];
}

extern "C" void kernel_launch(void* const* d_in, const int* in_sizes, int n_in,
                              void* d_out, int out_size, void* d_ws, size_t ws_size,
                              hipStream_t stream) {
    const float* x        = (const float*)d_in[0];
    const int*   ei       = (const int*)d_in[1];
    const float* edge_attr= (const float*)d_in[2];
    const float* W        = (const float*)d_in[3];
    const float* W_edge   = (const float*)d_in[4];
    const float* att_src  = (const float*)d_in[5];
    const float* att_dst  = (const float*)d_in[6];
    const float* att_edge = (const float*)d_in[7];
    const float* bias     = (const float*)d_in[8];
    const float* Wp       = (const float*)d_in[9];
    const float* bp       = (const float*)d_in[10];
    const float* gamma    = (const float*)d_in[11];
    const float* beta     = (const float*)d_in[12];
    float* out = (float*)d_out;

    int n = in_sizes[0] / EMB;
    int E = in_sizes[1] / 2;
    int nb = (n + 255) / 256;

    float* ws = (float*)d_ws;
    float* a_src       = ws; ws += (size_t)n * HEADS;
    float* a_dst       = ws; ws += (size_t)n * HEADS;
    float* we_att      = ws; ws += EDGE_DIM * HEADS;
    unsigned char* xwf8 = (unsigned char*)ws; ws += (size_t)n * HC / 4;   // 1B/elem
    uint4* recp        = (uint4*)ws; ws += (size_t)E * 4;    // 16B/edge
    unsigned short* WpT = (unsigned short*)ws; ws += HC * EMB / 2;
    unsigned short* WxT = (unsigned short*)ws; ws += NCOLS * EMB / 2;
    int* iw = (int*)ws;
    int* cnt       = iw; iw += n;
    int* rank      = iw; iw += E;
    int* row_start = iw; iw += n;
    int* tmp       = iw; iw += n;
    int* bsum      = iw; iw += 256;

    const int tb = 256;
    hipLaunchKernelGGL(k_prep, dim3((n + tb - 1) / tb), dim3(tb), 0, stream,
                       W_edge, att_edge, we_att, Wp, WpT, W, att_src, att_dst, WxT, cnt, n);
    hipLaunchKernelGGL(k_xw_mfma, dim3((n + 15) / 16), dim3(tb), 0, stream,
                       x, WxT, xwf8, a_src, a_dst, n, ei, cnt, rank, E);
    hipLaunchKernelGGL(k_scan1, dim3(nb), dim3(tb), 0, stream, cnt, tmp, bsum, n);
    hipLaunchKernelGGL(k_scan2, dim3(1), dim3(tb), 0, stream, bsum, nb);
    hipLaunchKernelGGL(k_scan3, dim3(nb), dim3(tb), 0, stream, tmp, cnt, bsum, row_start, n);
    hipLaunchKernelGGL(k_scatter, dim3((E + tb - 1) / tb), dim3(tb), 0, stream,
                       ei, edge_attr, we_att, a_src, a_dst, row_start, rank, recp, E);
    hipLaunchKernelGGL(k_gather_out, dim3((n + 3) / 4), dim3(tb), 0, stream,
                       row_start, cnt, recp, a_src, a_dst, xwf8, x, bias, WpT, bp,
                       gamma, beta, out, n);
}

// Round 13
// 187.124 us; speedup vs baseline: 2.2958x; 1.0028x over previous
//
#include <hip/hip_runtime.h>
#include <hip/hip_bf16.h>
#include <hip/hip_fp8.h>
#include <math.h>

#define EMB 64
#define HEADS 4
#define HC 256
#define EDGE_DIM 16
#define NEG_SLOPE 0.2f
#define LN_EPS 1e-5f
#define NCOLS 272   // 256 xw cols + 4 a_src + 4 a_dst + 8 pad
#define CAP 256     // records staged in LDS per chunk

typedef __attribute__((ext_vector_type(8))) short short8;
typedef __attribute__((ext_vector_type(4))) float f32x4;
typedef __attribute__((ext_vector_type(2))) float f32x2;

__device__ __forceinline__ float bflo(unsigned int u) { return __uint_as_float(u << 16); }
__device__ __forceinline__ float bfhi(unsigned int u) { return __uint_as_float(u & 0xffff0000u); }
__device__ __forceinline__ float bfu(unsigned short u) { return __uint_as_float((unsigned int)u << 16); }
__device__ __forceinline__ unsigned short bfb(float f) {
    __hip_bfloat16 h = __float2bfloat16(f);
    return *(unsigned short*)&h;
}
__device__ __forceinline__ unsigned int pack_bf2(float a, float b) {
    return (unsigned int)bfb(a) | ((unsigned int)bfb(b) << 16);
}
__device__ __forceinline__ unsigned char ftofp8(float f) {
    __hip_fp8_e4m3 t(f); return (unsigned char)t.__x;
}

// prep: zero cnt; we_att; WpT[64][256] bf16 (transposed Wp); WxT[272][64] bf16
__global__ void k_prep(const float* __restrict__ W_edge, const float* __restrict__ att_edge,
                       float* __restrict__ we_att, const float* __restrict__ Wp,
                       unsigned short* __restrict__ WpT, const float* __restrict__ W,
                       const float* __restrict__ att_src, const float* __restrict__ att_dst,
                       unsigned short* __restrict__ WxT, int* __restrict__ cnt, int n) {
    int i = blockIdx.x * blockDim.x + threadIdx.x;
    if (i < n) cnt[i] = 0;
    if (i < EDGE_DIM * HEADS) {
        int d = i >> 2, h = i & 3;
        float acc = 0.0f;
#pragma unroll
        for (int c = 0; c < EMB; ++c)
            acc += W_edge[d * HC + h * EMB + c] * att_edge[h * EMB + c];
        we_att[d * HEADS + h] = acc;
    }
    if (i < HC * EMB) {
        int k = i >> 8, jj = i & 255;              // WpT[k][jj] = Wp[jj][k]
        WpT[i] = bfb(Wp[jj * EMB + k]);
    }
    if (i < NCOLS * EMB) {
        int c = i >> 6, k = i & 63;
        float v = 0.0f;
        if (c < HC) {
            v = W[k * HC + c];
        } else if (c < HC + 4) {
            int h = c - HC;
            float s = 0.0f;
#pragma unroll
            for (int j = 0; j < EMB; ++j) s += W[k * HC + h * EMB + j] * att_src[h * EMB + j];
            v = s;
        } else if (c < HC + 8) {
            int h = c - HC - 4;
            float s = 0.0f;
#pragma unroll
            for (int j = 0; j < EMB; ++j) s += W[k * HC + h * EMB + j] * att_dst[h * EMB + j];
            v = s;
        }
        WxT[i] = bfb(v);
    }
}

// ---- MFMA GEMM: [xw(fp8) | a_src | a_dst] = x @ Wx ; 16 nodes/block, 4 waves ----
// fused tail: dst-histogram rank atomic (one edge per thread, grid-stride)
__global__ void __launch_bounds__(256)
k_xw_mfma(const float* __restrict__ x, const unsigned short* __restrict__ WxT,
          unsigned char* __restrict__ xwf8, float* __restrict__ a_src,
          float* __restrict__ a_dst, int n,
          const int* __restrict__ ei, int* __restrict__ cnt,
          int* __restrict__ rank, int E) {
    int tid = threadIdx.x, lane = tid & 63, wv = tid >> 6;
    int g = lane >> 4, r16 = lane & 15;
    int mbase = blockIdx.x * 16;
    int row = mbase + r16;
    if (row >= n) row = n - 1;

    const float* xr = x + (size_t)row * EMB;
    short8 A[2];
#pragma unroll
    for (int kk = 0; kk < 2; ++kk) {
        float4 f0 = *(const float4*)(xr + kk * 32 + 8 * g);
        float4 f1 = *(const float4*)(xr + kk * 32 + 8 * g + 4);
        short8 a;
        a[0] = (short)bfb(f0.x); a[1] = (short)bfb(f0.y);
        a[2] = (short)bfb(f0.z); a[3] = (short)bfb(f0.w);
        a[4] = (short)bfb(f1.x); a[5] = (short)bfb(f1.y);
        a[6] = (short)bfb(f1.z); a[7] = (short)bfb(f1.w);
        A[kk] = a;
    }

    for (int t = wv; t <= 16; t += 4) {
        int col = t * 16 + r16;
        const unsigned short* bp = WxT + (size_t)col * EMB + 8 * g;
        short8 B0 = *(const short8*)(bp);
        short8 B1 = *(const short8*)(bp + 32);
        f32x4 acc = {0.f, 0.f, 0.f, 0.f};
        acc = __builtin_amdgcn_mfma_f32_16x16x32_bf16(A[0], B0, acc, 0, 0, 0);
        acc = __builtin_amdgcn_mfma_f32_16x16x32_bf16(A[1], B1, acc, 0, 0, 0);
        if (t < 16) {
#pragma unroll
            for (int r = 0; r < 4; ++r) {
                int node = mbase + 4 * g + r;
                if (node < n) xwf8[(size_t)node * HC + col] = ftofp8(acc[r]);
            }
        } else {
#pragma unroll
            for (int r = 0; r < 4; ++r) {
                int node = mbase + 4 * g + r;
                if (node < n) {
                    if (r16 < 4) a_src[node * HEADS + r16] = acc[r];
                    else if (r16 < 8) a_dst[node * HEADS + r16 - 4] = acc[r];
                }
            }
        }
    }

    // fused histogram: rank of each edge within its dst bucket
    int stride = gridDim.x * blockDim.x;
    for (int e = blockIdx.x * blockDim.x + tid; e < E; e += stride)
        rank[e] = atomicAdd(&cnt[ei[E + e]], 1);
}

// ---------------- 3-dispatch exclusive scan over cnt[n] ----------------
__global__ void k_scan1(const int* __restrict__ cnt, int* __restrict__ tmp,
                        int* __restrict__ bsum, int n) {
    __shared__ int s[256];
    int i = blockIdx.x * 256 + threadIdx.x;
    int v = (i < n) ? cnt[i] : 0;
    s[threadIdx.x] = v;
    __syncthreads();
    for (int off = 1; off < 256; off <<= 1) {
        int t = (threadIdx.x >= off) ? s[threadIdx.x - off] : 0;
        __syncthreads();
        s[threadIdx.x] += t;
        __syncthreads();
    }
    if (i < n) tmp[i] = s[threadIdx.x];
    if (threadIdx.x == 255) bsum[blockIdx.x] = s[255];
}

__global__ void k_scan2(int* __restrict__ bsum, int nb) {
    __shared__ int s[256];
    int v = (threadIdx.x < nb) ? bsum[threadIdx.x] : 0;
    s[threadIdx.x] = v;
    __syncthreads();
    for (int off = 1; off < 256; off <<= 1) {
        int t = (threadIdx.x >= off) ? s[threadIdx.x - off] : 0;
        __syncthreads();
        s[threadIdx.x] += t;
        __syncthreads();
    }
    if (threadIdx.x < nb) bsum[threadIdx.x] = s[threadIdx.x] - v; // exclusive
}

__global__ void k_scan3(const int* __restrict__ tmp, const int* __restrict__ cnt,
                        const int* __restrict__ bsum, int* __restrict__ row_start, int n) {
    int i = blockIdx.x * 256 + threadIdx.x;
    if (i < n) row_start[i] = tmp[i] - cnt[i] + bsum[blockIdx.x];
}

// ---- scatter: alpha math + 16B CSR record write (no atomics) ----
// record = { ea01.bf16x2, ea23.bf16x2, src.u32, ae.int8x4 (scale 1/32) }
__global__ void k_scatter(const int* __restrict__ ei, const float* __restrict__ edge_attr,
                          const float* __restrict__ we_att, const float* __restrict__ a_src,
                          const float* __restrict__ a_dst, const int* __restrict__ row_start,
                          const int* __restrict__ rank, uint4* __restrict__ recp, int E) {
    __shared__ float wa[EDGE_DIM * HEADS];
    if (threadIdx.x < EDGE_DIM * HEADS) wa[threadIdx.x] = we_att[threadIdx.x];
    __syncthreads();
    int e = blockIdx.x * blockDim.x + threadIdx.x;
    if (e >= E) return;
    int s = ei[e], d = ei[E + e];
    const float4* ea4 = (const float4*)(edge_attr + (size_t)e * EDGE_DIM);
    float ae[HEADS] = {0.f, 0.f, 0.f, 0.f};
#pragma unroll
    for (int q = 0; q < 4; ++q) {
        float4 v4 = ea4[q];
        const float* vp = (const float*)&v4;
#pragma unroll
        for (int r = 0; r < 4; ++r) {
            float v = vp[r];
            int dd = q * 4 + r;
#pragma unroll
            for (int h = 0; h < HEADS; ++h) ae[h] += v * wa[dd * HEADS + h];
        }
    }
    float4 as4 = *(const float4*)(a_src + (size_t)s * HEADS);
    float4 ad4 = *(const float4*)(a_dst + (size_t)d * HEADS);
    const float* asp = (const float*)&as4;
    const float* adp = (const float*)&ad4;
    float ea[HEADS];
    unsigned int aeq = 0;
#pragma unroll
    for (int h = 0; h < HEADS; ++h) {
        float al = asp[h] + adp[h] + ae[h];
        al = al >= 0.0f ? al : NEG_SLOPE * al;
        ea[h] = __expf(al);          // no max-subtraction needed: |al| < ~8
        int q = __float2int_rn(ae[h] * 32.0f);
        q = max(-127, min(127, q));
        aeq |= ((unsigned int)(q & 0xff)) << (8 * h);
    }
    int pos = row_start[d] + rank[e];
    uint4 w;
    w.x = pack_bf2(ea[0], ea[1]);
    w.y = pack_bf2(ea[2], ea[3]);
    w.z = (unsigned int)s;
    w.w = aeq;
    recp[pos] = w;
}

// two-phase gather batch: issue D independent row loads, then decode+accumulate
template<int D>
__device__ __forceinline__ void gather_batch(
    const uint4* recs, int o, int j, const unsigned char* xwf8, int lane,
    int h4, bool hodd, int sh1,
    float& acc0, float& acc1, float& acc2, float& acc3, float& dn, float& aeS) {
    int sv[D];
#pragma unroll
    for (int u = 0; u < D; ++u) sv[u] = (int)recs[o + j + u].z;
    unsigned int rv[D];
#pragma unroll
    for (int u = 0; u < D; ++u)
        rv[u] = *(const unsigned int*)(xwf8 + (size_t)sv[u] * HC + (lane << 2));
#pragma unroll
    for (int u = 0; u < D; ++u) {
        uint4 W = recs[o + j + u];
        unsigned sel = (h4 & 2) ? W.y : W.x;
        float a = hodd ? bfhi(sel) : bflo(sel);
        aeS += (float)((int)(W.w << sh1) >> 24);
        dn += a;
        f32x2 lo2 = __builtin_amdgcn_cvt_pk_f32_fp8((int)rv[u], false);
        f32x2 hi2 = __builtin_amdgcn_cvt_pk_f32_fp8((int)rv[u], true);
        acc0 += a * lo2.x; acc1 += a * lo2.y;
        acc2 += a * hi2.x; acc3 += a * hi2.y;
    }
}

// ------- fused gather (LDS-staged records) + softmax + aggregate + MFMA proj + LN -------
// 256 threads: 4 nodes/block, 1 wave/node; xw rows are fp8 e4m3 (256B)
__global__ void __launch_bounds__(256)
k_gather_out(const int* __restrict__ row_start, const int* __restrict__ cnt,
             const uint4* __restrict__ recp,
             const float* __restrict__ a_src, const float* __restrict__ a_dst,
             const unsigned char* __restrict__ xwf8, const float* __restrict__ x,
             const float* __restrict__ bias, const unsigned short* __restrict__ WpT,
             const float* __restrict__ bp, const float* __restrict__ gamma,
             const float* __restrict__ beta, float* __restrict__ out, int n) {
    int tid = threadIdx.x, lane = tid & 63, wv = tid >> 6;
    int node = blockIdx.x * 4 + wv;
    bool valid = node < n;
    int nodeC = valid ? node : n - 1;
    int h4 = lane >> 4;
    bool hodd = (h4 & 1);
    int sh1 = (3 - h4) * 8;

    __shared__ __align__(16) uint4 recs[CAP];
    __shared__ __align__(16) unsigned short gbf[4][272];
    __shared__ float pC[4][66];

    // block's contiguous record range
    int first = blockIdx.x * 4;
    int last = min(first + 4, n) - 1;
    int rs0 = row_start[first];
    int total = row_start[last] + cnt[last] - rs0;

    int dg = valid ? cnt[nodeC] : 0;
    int myLo = row_start[nodeC] - rs0;
    int myHi = myLo + dg;

    // hoisted self-node loads
    float as = a_src[nodeC * HEADS + h4];
    float ad = a_dst[nodeC * HEADS + h4];
    unsigned int sr8 = *(const unsigned int*)(xwf8 + (size_t)nodeC * HC + (lane << 2));
    float4 bv = *(const float4*)(bias + (lane << 2));

    float acc0 = 0.f, acc1 = 0.f, acc2 = 0.f, acc3 = 0.f;
    float dn = 0.f, aeS = 0.f;

    for (int base = 0; base < total; base += CAP) {
        int cend = min(total, base + CAP);
        if (base) __syncthreads();
        for (int idx = base + tid; idx < cend; idx += 256)
            recs[idx - base] = recp[rs0 + idx];
        __syncthreads();
        int lo = max(myLo, base), hi = min(myHi, cend);
        int c = hi - lo;
        int o = lo - base;
        int j = 0;
        for (; j + 16 <= c; j += 16)
            gather_batch<16>(recs, o, j, xwf8, lane, h4, hodd, sh1,
                             acc0, acc1, acc2, acc3, dn, aeS);
        if (j + 8 <= c) {
            gather_batch<8>(recs, o, j, xwf8, lane, h4, hodd, sh1,
                            acc0, acc1, acc2, acc3, dn, aeS);
            j += 8;
        }
        if (j + 4 <= c) {
            gather_batch<4>(recs, o, j, xwf8, lane, h4, hodd, sh1,
                            acc0, acc1, acc2, acc3, dn, aeS);
            j += 4;
        }
        for (; j < c; ++j)
            gather_batch<1>(recs, o, j, xwf8, lane, h4, hodd, sh1,
                            acc0, acc1, acc2, acc3, dn, aeS);
    }

    // self-loop + normalize + bias -> bf16 g in LDS
    float cf = fmaxf((float)dg, 1.0f);
    float al = as + ad + (aeS * (1.0f / 32.0f)) / cf;
    al = al >= 0.f ? al : NEG_SLOPE * al;
    float el = __expf(al);
    float inv = 1.0f / (dn + el);
    f32x2 slo = __builtin_amdgcn_cvt_pk_f32_fp8((int)sr8, false);
    f32x2 shi = __builtin_amdgcn_cvt_pk_f32_fp8((int)sr8, true);
    ushort4 gv;
    gv.x = bfb((acc0 + el * slo.x) * inv + bv.x);
    gv.y = bfb((acc1 + el * slo.y) * inv + bv.y);
    gv.z = bfb((acc2 + el * shi.x) * inv + bv.z);
    gv.w = bfb((acc3 + el * shi.y) * inv + bv.w);
    *(ushort4*)&gbf[wv][lane << 2] = gv;
    __syncthreads();

    // MFMA projection: wave wv computes col tile wv (16 cols) of g(4x256) @ Wp(256x64)
    {
        int g = lane >> 4, r16 = lane & 15;
        const unsigned short* wp = WpT + (size_t)(wv * 16 + r16) * HC + 8 * g;
        const unsigned short* ga = &gbf[r16 & 3][8 * g];
        f32x4 pacc = {0.f, 0.f, 0.f, 0.f};
#pragma unroll
        for (int kk = 0; kk < 8; ++kk) {
            short8 Af = *(const short8*)(ga + kk * 32);
            short8 Bf = *(const short8*)(wp + kk * 32);
            pacc = __builtin_amdgcn_mfma_f32_16x16x32_bf16(Af, Bf, pacc, 0, 0, 0);
        }
        if (g == 0) {
#pragma unroll
            for (int m = 0; m < 4; ++m) pC[m][wv * 16 + r16] = pacc[m];
        }
    }
    __syncthreads();

    // epilogue: wave wv -> node wv; lane = channel
    float p = pC[wv][lane] + bp[lane];
    float elv = p > 0.f ? p : expm1f(p);
    float xv = valid ? x[(size_t)node * EMB + lane] : 0.f;
    float hv = xv + elv;
    float s1 = hv, s2 = hv * hv;
    for (int off = 32; off > 0; off >>= 1) {
        s1 += __shfl_xor(s1, off);
        s2 += __shfl_xor(s2, off);
    }
    float mu = s1 * (1.0f / EMB);
    float var = s2 * (1.0f / EMB) - mu * mu;
    if (valid)
        out[(size_t)node * EMB + lane] = (hv - mu) * rsqrtf(var + LN_EPS) * gamma[lane] + beta[lane];
}

extern "C" void kernel_launch(void* const* d_in, const int* in_sizes, int n_in,
                              void* d_out, int out_size, void* d_ws, size_t ws_size,
                              hipStream_t stream) {
    const float* x        = (const float*)d_in[0];
    const int*   ei       = (const int*)d_in[1];
    const float* edge_attr= (const float*)d_in[2];
    const float* W        = (const float*)d_in[3];
    const float* W_edge   = (const float*)d_in[4];
    const float* att_src  = (const float*)d_in[5];
    const float* att_dst  = (const float*)d_in[6];
    const float* att_edge = (const float*)d_in[7];
    const float* bias     = (const float*)d_in[8];
    const float* Wp       = (const float*)d_in[9];
    const float* bp       = (const float*)d_in[10];
    const float* gamma    = (const float*)d_in[11];
    const float* beta     = (const float*)d_in[12];
    float* out = (float*)d_out;

    int n = in_sizes[0] / EMB;
    int E = in_sizes[1] / 2;
    int nb = (n + 255) / 256;

    float* ws = (float*)d_ws;
    float* a_src       = ws; ws += (size_t)n * HEADS;
    float* a_dst       = ws; ws += (size_t)n * HEADS;
    float* we_att      = ws; ws += EDGE_DIM * HEADS;
    unsigned char* xwf8 = (unsigned char*)ws; ws += (size_t)n * HC / 4;   // 1B/elem
    uint4* recp        = (uint4*)ws; ws += (size_t)E * 4;    // 16B/edge
    unsigned short* WpT = (unsigned short*)ws; ws += HC * EMB / 2;
    unsigned short* WxT = (unsigned short*)ws; ws += NCOLS * EMB / 2;
    int* iw = (int*)ws;
    int* cnt       = iw; iw += n;
    int* rank      = iw; iw += E;
    int* row_start = iw; iw += n;
    int* tmp       = iw; iw += n;
    int* bsum      = iw; iw += 256;

    const int tb = 256;
    hipLaunchKernelGGL(k_prep, dim3((n + tb - 1) / tb), dim3(tb), 0, stream,
                       W_edge, att_edge, we_att, Wp, WpT, W, att_src, att_dst, WxT, cnt, n);
    hipLaunchKernelGGL(k_xw_mfma, dim3((n + 15) / 16), dim3(tb), 0, stream,
                       x, WxT, xwf8, a_src, a_dst, n, ei, cnt, rank, E);
    hipLaunchKernelGGL(k_scan1, dim3(nb), dim3(tb), 0, stream, cnt, tmp, bsum, n);
    hipLaunchKernelGGL(k_scan2, dim3(1), dim3(tb), 0, stream, bsum, nb);
    hipLaunchKernelGGL(k_scan3, dim3(nb), dim3(tb), 0, stream, tmp, cnt, bsum, row_start, n);
    hipLaunchKernelGGL(k_scatter, dim3((E + tb - 1) / tb), dim3(tb), 0, stream,
                       ei, edge_attr, we_att, a_src, a_dst, row_start, rank, recp, E);
    hipLaunchKernelGGL(k_gather_out, dim3((n + 3) / 4), dim3(tb), 0, stream,
                       row_start, cnt, recp, a_src, a_dst, xwf8, x, bias, WpT, bp,
                       gamma, beta, out, n);
}

// Round 14
// 161.334 us; speedup vs baseline: 2.6627x; 1.1599x over previous
//
#include <hip/hip_runtime.h>
#include <hip/hip_bf16.h>
#include <hip/hip_fp8.h>
#include <math.h>

#define EMB 64
#define HEADS 4
#define HC 256
#define EDGE_DIM 16
#define NEG_SLOPE 0.2f
#define LN_EPS 1e-5f
#define NCOLS 272   // 256 xw cols + 4 a_src + 4 a_dst + 8 pad
#define CAP 512     // records staged in LDS per chunk
#define NPB 16      // nodes per block (4 per wave)

typedef __attribute__((ext_vector_type(8))) short short8;
typedef __attribute__((ext_vector_type(4))) float f32x4;
typedef __attribute__((ext_vector_type(2))) float f32x2;

__device__ __forceinline__ float bflo(unsigned int u) { return __uint_as_float(u << 16); }
__device__ __forceinline__ float bfhi(unsigned int u) { return __uint_as_float(u & 0xffff0000u); }
__device__ __forceinline__ unsigned short bfb(float f) {
    __hip_bfloat16 h = __float2bfloat16(f);
    return *(unsigned short*)&h;
}
__device__ __forceinline__ unsigned int pack_bf2(float a, float b) {
    return (unsigned int)bfb(a) | ((unsigned int)bfb(b) << 16);
}
__device__ __forceinline__ unsigned char ftofp8(float f) {
    __hip_fp8_e4m3 t(f); return (unsigned char)t.__x;
}

// prep: zero cnt; we_att; WpT[64][256] bf16 (transposed Wp); WxT[272][64] bf16
__global__ void k_prep(const float* __restrict__ W_edge, const float* __restrict__ att_edge,
                       float* __restrict__ we_att, const float* __restrict__ Wp,
                       unsigned short* __restrict__ WpT, const float* __restrict__ W,
                       const float* __restrict__ att_src, const float* __restrict__ att_dst,
                       unsigned short* __restrict__ WxT, int* __restrict__ cnt, int n) {
    int i = blockIdx.x * blockDim.x + threadIdx.x;
    if (i < n) cnt[i] = 0;
    if (i < EDGE_DIM * HEADS) {
        int d = i >> 2, h = i & 3;
        float acc = 0.0f;
#pragma unroll
        for (int c = 0; c < EMB; ++c)
            acc += W_edge[d * HC + h * EMB + c] * att_edge[h * EMB + c];
        we_att[d * HEADS + h] = acc;
    }
    if (i < HC * EMB) {
        int k = i >> 8, jj = i & 255;              // WpT[k][jj] = Wp[jj][k]
        WpT[i] = bfb(Wp[jj * EMB + k]);
    }
    if (i < NCOLS * EMB) {
        int c = i >> 6, k = i & 63;
        float v = 0.0f;
        if (c < HC) {
            v = W[k * HC + c];
        } else if (c < HC + 4) {
            int h = c - HC;
            float s = 0.0f;
#pragma unroll
            for (int j = 0; j < EMB; ++j) s += W[k * HC + h * EMB + j] * att_src[h * EMB + j];
            v = s;
        } else if (c < HC + 8) {
            int h = c - HC - 4;
            float s = 0.0f;
#pragma unroll
            for (int j = 0; j < EMB; ++j) s += W[k * HC + h * EMB + j] * att_dst[h * EMB + j];
            v = s;
        }
        WxT[i] = bfb(v);
    }
}

// ---- MFMA GEMM: [xw(fp8) | a_src | a_dst] = x @ Wx ; 16 nodes/block, 4 waves ----
// fused tail: dst-histogram rank atomic (one edge per thread, grid-stride)
__global__ void __launch_bounds__(256)
k_xw_mfma(const float* __restrict__ x, const unsigned short* __restrict__ WxT,
          unsigned char* __restrict__ xwf8, float* __restrict__ a_src,
          float* __restrict__ a_dst, int n,
          const int* __restrict__ ei, int* __restrict__ cnt,
          int* __restrict__ rank, int E) {
    int tid = threadIdx.x, lane = tid & 63, wv = tid >> 6;
    int g = lane >> 4, r16 = lane & 15;
    int mbase = blockIdx.x * 16;
    int row = mbase + r16;
    if (row >= n) row = n - 1;

    const float* xr = x + (size_t)row * EMB;
    short8 A[2];
#pragma unroll
    for (int kk = 0; kk < 2; ++kk) {
        float4 f0 = *(const float4*)(xr + kk * 32 + 8 * g);
        float4 f1 = *(const float4*)(xr + kk * 32 + 8 * g + 4);
        short8 a;
        a[0] = (short)bfb(f0.x); a[1] = (short)bfb(f0.y);
        a[2] = (short)bfb(f0.z); a[3] = (short)bfb(f0.w);
        a[4] = (short)bfb(f1.x); a[5] = (short)bfb(f1.y);
        a[6] = (short)bfb(f1.z); a[7] = (short)bfb(f1.w);
        A[kk] = a;
    }

    for (int t = wv; t <= 16; t += 4) {
        int col = t * 16 + r16;
        const unsigned short* bp = WxT + (size_t)col * EMB + 8 * g;
        short8 B0 = *(const short8*)(bp);
        short8 B1 = *(const short8*)(bp + 32);
        f32x4 acc = {0.f, 0.f, 0.f, 0.f};
        acc = __builtin_amdgcn_mfma_f32_16x16x32_bf16(A[0], B0, acc, 0, 0, 0);
        acc = __builtin_amdgcn_mfma_f32_16x16x32_bf16(A[1], B1, acc, 0, 0, 0);
        if (t < 16) {
#pragma unroll
            for (int r = 0; r < 4; ++r) {
                int node = mbase + 4 * g + r;
                if (node < n) xwf8[(size_t)node * HC + col] = ftofp8(acc[r]);
            }
        } else {
#pragma unroll
            for (int r = 0; r < 4; ++r) {
                int node = mbase + 4 * g + r;
                if (node < n) {
                    if (r16 < 4) a_src[node * HEADS + r16] = acc[r];
                    else if (r16 < 8) a_dst[node * HEADS + r16 - 4] = acc[r];
                }
            }
        }
    }

    // fused histogram: rank of each edge within its dst bucket
    int stride = gridDim.x * blockDim.x;
    for (int e = blockIdx.x * blockDim.x + tid; e < E; e += stride)
        rank[e] = atomicAdd(&cnt[ei[E + e]], 1);
}

// ---------------- 3-dispatch exclusive scan over cnt[n] ----------------
__global__ void k_scan1(const int* __restrict__ cnt, int* __restrict__ tmp,
                        int* __restrict__ bsum, int n) {
    __shared__ int s[256];
    int i = blockIdx.x * 256 + threadIdx.x;
    int v = (i < n) ? cnt[i] : 0;
    s[threadIdx.x] = v;
    __syncthreads();
    for (int off = 1; off < 256; off <<= 1) {
        int t = (threadIdx.x >= off) ? s[threadIdx.x - off] : 0;
        __syncthreads();
        s[threadIdx.x] += t;
        __syncthreads();
    }
    if (i < n) tmp[i] = s[threadIdx.x];
    if (threadIdx.x == 255) bsum[blockIdx.x] = s[255];
}

__global__ void k_scan2(int* __restrict__ bsum, int nb) {
    __shared__ int s[256];
    int v = (threadIdx.x < nb) ? bsum[threadIdx.x] : 0;
    s[threadIdx.x] = v;
    __syncthreads();
    for (int off = 1; off < 256; off <<= 1) {
        int t = (threadIdx.x >= off) ? s[threadIdx.x - off] : 0;
        __syncthreads();
        s[threadIdx.x] += t;
        __syncthreads();
    }
    if (threadIdx.x < nb) bsum[threadIdx.x] = s[threadIdx.x] - v; // exclusive
}

__global__ void k_scan3(const int* __restrict__ tmp, const int* __restrict__ cnt,
                        const int* __restrict__ bsum, int* __restrict__ row_start, int n) {
    int i = blockIdx.x * 256 + threadIdx.x;
    if (i < n) row_start[i] = tmp[i] - cnt[i] + bsum[blockIdx.x];
}

// ---- scatter: alpha math + 16B CSR record write (no atomics) ----
// record = { ea01.bf16x2, ea23.bf16x2, src.u32, ae.int8x4 (scale 1/32) }
__global__ void k_scatter(const int* __restrict__ ei, const float* __restrict__ edge_attr,
                          const float* __restrict__ we_att, const float* __restrict__ a_src,
                          const float* __restrict__ a_dst, const int* __restrict__ row_start,
                          const int* __restrict__ rank, uint4* __restrict__ recp, int E) {
    __shared__ float wa[EDGE_DIM * HEADS];
    if (threadIdx.x < EDGE_DIM * HEADS) wa[threadIdx.x] = we_att[threadIdx.x];
    __syncthreads();
    int e = blockIdx.x * blockDim.x + threadIdx.x;
    if (e >= E) return;
    int s = ei[e], d = ei[E + e];
    const float4* ea4 = (const float4*)(edge_attr + (size_t)e * EDGE_DIM);
    float ae[HEADS] = {0.f, 0.f, 0.f, 0.f};
#pragma unroll
    for (int q = 0; q < 4; ++q) {
        float4 v4 = ea4[q];
        const float* vp = (const float*)&v4;
#pragma unroll
        for (int r = 0; r < 4; ++r) {
            float v = vp[r];
            int dd = q * 4 + r;
#pragma unroll
            for (int h = 0; h < HEADS; ++h) ae[h] += v * wa[dd * HEADS + h];
        }
    }
    float4 as4 = *(const float4*)(a_src + (size_t)s * HEADS);
    float4 ad4 = *(const float4*)(a_dst + (size_t)d * HEADS);
    const float* asp = (const float*)&as4;
    const float* adp = (const float*)&ad4;
    float ea[HEADS];
    unsigned int aeq = 0;
#pragma unroll
    for (int h = 0; h < HEADS; ++h) {
        float al = asp[h] + adp[h] + ae[h];
        al = al >= 0.0f ? al : NEG_SLOPE * al;
        ea[h] = __expf(al);          // no max-subtraction needed: |al| < ~8
        int q = __float2int_rn(ae[h] * 32.0f);
        q = max(-127, min(127, q));
        aeq |= ((unsigned int)(q & 0xff)) << (8 * h);
    }
    int pos = row_start[d] + rank[e];
    uint4 w;
    w.x = pack_bf2(ea[0], ea[1]);
    w.y = pack_bf2(ea[2], ea[3]);
    w.z = (unsigned int)s;
    w.w = aeq;
    recp[pos] = w;
}

// two-phase gather batch: issue D independent row loads, then decode+accumulate
template<int D>
__device__ __forceinline__ void gather_batch(
    const uint4* recs, int o, int j, const unsigned char* xwf8, int lane,
    int h4, bool hodd, int sh1,
    float& acc0, float& acc1, float& acc2, float& acc3, float& dn, float& aeS) {
    int sv[D];
#pragma unroll
    for (int u = 0; u < D; ++u) sv[u] = (int)recs[o + j + u].z;
    unsigned int rv[D];
#pragma unroll
    for (int u = 0; u < D; ++u)
        rv[u] = *(const unsigned int*)(xwf8 + (size_t)sv[u] * HC + (lane << 2));
#pragma unroll
    for (int u = 0; u < D; ++u) {
        uint4 W = recs[o + j + u];
        unsigned sel = (h4 & 2) ? W.y : W.x;
        float a = hodd ? bfhi(sel) : bflo(sel);
        aeS += (float)((int)(W.w << sh1) >> 24);
        dn += a;
        f32x2 lo2 = __builtin_amdgcn_cvt_pk_f32_fp8((int)rv[u], false);
        f32x2 hi2 = __builtin_amdgcn_cvt_pk_f32_fp8((int)rv[u], true);
        acc0 += a * lo2.x; acc1 += a * lo2.y;
        acc2 += a * hi2.x; acc3 += a * hi2.y;
    }
}

// process one node's record sub-range [lo,hi) within the staged chunk
__device__ __forceinline__ void node_range(
    const uint4* recs, int o, int c, const unsigned char* xwf8, int lane,
    int h4, bool hodd, int sh1,
    float& acc0, float& acc1, float& acc2, float& acc3, float& dn, float& aeS) {
    int j = 0;
    for (; j + 16 <= c; j += 16)
        gather_batch<16>(recs, o, j, xwf8, lane, h4, hodd, sh1, acc0, acc1, acc2, acc3, dn, aeS);
    if (j + 8 <= c) {
        gather_batch<8>(recs, o, j, xwf8, lane, h4, hodd, sh1, acc0, acc1, acc2, acc3, dn, aeS);
        j += 8;
    }
    if (j + 4 <= c) {
        gather_batch<4>(recs, o, j, xwf8, lane, h4, hodd, sh1, acc0, acc1, acc2, acc3, dn, aeS);
        j += 4;
    }
    for (; j < c; ++j)
        gather_batch<1>(recs, o, j, xwf8, lane, h4, hodd, sh1, acc0, acc1, acc2, acc3, dn, aeS);
}

// ------- fused gather + softmax + aggregate + MFMA proj + LN -------
// 256 threads: 16 nodes/block, each wave owns 4 contiguous nodes
__global__ void __launch_bounds__(256)
k_gather_out(const int* __restrict__ row_start, const int* __restrict__ cnt,
             const uint4* __restrict__ recp,
             const float* __restrict__ a_src, const float* __restrict__ a_dst,
             const unsigned char* __restrict__ xwf8, const float* __restrict__ x,
             const float* __restrict__ bias, const unsigned short* __restrict__ WpT,
             const float* __restrict__ bp, const float* __restrict__ gamma,
             const float* __restrict__ beta, float* __restrict__ out, int n) {
    int tid = threadIdx.x, lane = tid & 63, wv = tid >> 6;
    int h4 = lane >> 4;
    bool hodd = (h4 & 1);
    int sh1 = (3 - h4) * 8;

    __shared__ __align__(16) uint4 recs[CAP];
    __shared__ __align__(16) unsigned short gbf[NPB][272];
    __shared__ float pC[NPB][66];

    int first = blockIdx.x * NPB;
    int last = min(first + NPB, n) - 1;
    int rs0 = row_start[first];
    int total = row_start[last] + cnt[last] - rs0;

    // this wave's 4 nodes (contiguous)
    int nd[4], dgq[4], mLo[4], mHi[4];
#pragma unroll
    for (int q = 0; q < 4; ++q) {
        int node = first + wv * 4 + q;
        bool v = node < n;
        int nc = v ? node : n - 1;
        nd[q] = nc;
        dgq[q] = v ? cnt[nc] : 0;
        mLo[q] = row_start[nc] - rs0;
        mHi[q] = mLo[q] + dgq[q];
    }

    float a00 = 0.f, a01 = 0.f, a02 = 0.f, a03 = 0.f, dn0 = 0.f, ae0 = 0.f;
    float a10 = 0.f, a11 = 0.f, a12 = 0.f, a13 = 0.f, dn1 = 0.f, ae1 = 0.f;
    float a20 = 0.f, a21 = 0.f, a22 = 0.f, a23 = 0.f, dn2 = 0.f, ae2 = 0.f;
    float a30 = 0.f, a31 = 0.f, a32 = 0.f, a33 = 0.f, dn3 = 0.f, ae3 = 0.f;

    for (int base = 0; base < total; base += CAP) {
        int cend = min(total, base + CAP);
        if (base) __syncthreads();
        for (int idx = base + tid; idx < cend; idx += 256)
            recs[idx - base] = recp[rs0 + idx];
        __syncthreads();
        {
            int lo = max(mLo[0], base), hi = min(mHi[0], cend);
            if (hi > lo) node_range(recs, lo - base, hi - lo, xwf8, lane, h4, hodd, sh1,
                                    a00, a01, a02, a03, dn0, ae0);
        }
        {
            int lo = max(mLo[1], base), hi = min(mHi[1], cend);
            if (hi > lo) node_range(recs, lo - base, hi - lo, xwf8, lane, h4, hodd, sh1,
                                    a10, a11, a12, a13, dn1, ae1);
        }
        {
            int lo = max(mLo[2], base), hi = min(mHi[2], cend);
            if (hi > lo) node_range(recs, lo - base, hi - lo, xwf8, lane, h4, hodd, sh1,
                                    a20, a21, a22, a23, dn2, ae2);
        }
        {
            int lo = max(mLo[3], base), hi = min(mHi[3], cend);
            if (hi > lo) node_range(recs, lo - base, hi - lo, xwf8, lane, h4, hodd, sh1,
                                    a30, a31, a32, a33, dn3, ae3);
        }
    }

    // finalize each of the wave's 4 nodes: self-loop + normalize + bias -> bf16 g
    float4 bv = *(const float4*)(bias + (lane << 2));
#pragma unroll
    for (int q = 0; q < 4; ++q) {
        float A0 = (q == 0) ? a00 : (q == 1) ? a10 : (q == 2) ? a20 : a30;
        float A1 = (q == 0) ? a01 : (q == 1) ? a11 : (q == 2) ? a21 : a31;
        float A2 = (q == 0) ? a02 : (q == 1) ? a12 : (q == 2) ? a22 : a32;
        float A3 = (q == 0) ? a03 : (q == 1) ? a13 : (q == 2) ? a23 : a33;
        float DN = (q == 0) ? dn0 : (q == 1) ? dn1 : (q == 2) ? dn2 : dn3;
        float AE = (q == 0) ? ae0 : (q == 1) ? ae1 : (q == 2) ? ae2 : ae3;
        int nc = nd[q];
        float as = a_src[nc * HEADS + h4];
        float ad = a_dst[nc * HEADS + h4];
        unsigned int sr8 = *(const unsigned int*)(xwf8 + (size_t)nc * HC + (lane << 2));
        float cf = fmaxf((float)dgq[q], 1.0f);
        float al = as + ad + (AE * (1.0f / 32.0f)) / cf;
        al = al >= 0.f ? al : NEG_SLOPE * al;
        float el = __expf(al);
        float inv = 1.0f / (DN + el);
        f32x2 slo = __builtin_amdgcn_cvt_pk_f32_fp8((int)sr8, false);
        f32x2 shi = __builtin_amdgcn_cvt_pk_f32_fp8((int)sr8, true);
        ushort4 gv;
        gv.x = bfb((A0 + el * slo.x) * inv + bv.x);
        gv.y = bfb((A1 + el * slo.y) * inv + bv.y);
        gv.z = bfb((A2 + el * shi.x) * inv + bv.z);
        gv.w = bfb((A3 + el * shi.y) * inv + bv.w);
        *(ushort4*)&gbf[wv * 4 + q][lane << 2] = gv;
    }
    __syncthreads();

    // MFMA projection: full M=16. wave wv computes col tile wv of g(16x256) @ Wp(256x64)
    {
        int g = lane >> 4, r16 = lane & 15;
        const unsigned short* wp = WpT + (size_t)(wv * 16 + r16) * HC + 8 * g;
        const unsigned short* ga = &gbf[r16][8 * g];
        f32x4 pacc = {0.f, 0.f, 0.f, 0.f};
#pragma unroll
        for (int kk = 0; kk < 8; ++kk) {
            short8 Af = *(const short8*)(ga + kk * 32);
            short8 Bf = *(const short8*)(wp + kk * 32);
            pacc = __builtin_amdgcn_mfma_f32_16x16x32_bf16(Af, Bf, pacc, 0, 0, 0);
        }
#pragma unroll
        for (int m = 0; m < 4; ++m) pC[4 * g + m][wv * 16 + r16] = pacc[m];
    }
    __syncthreads();

    // epilogue: 4 passes; pass p -> local node wv + 4p; lane = channel
#pragma unroll
    for (int p = 0; p < 4; ++p) {
        int local = wv + 4 * p;
        int node = first + local;
        bool v2 = node < n;
        float pv = pC[local][lane] + bp[lane];
        float elv = pv > 0.f ? pv : expm1f(pv);
        float xv = v2 ? x[(size_t)node * EMB + lane] : 0.f;
        float hv = xv + elv;
        float s1 = hv, s2 = hv * hv;
        for (int off = 32; off > 0; off >>= 1) {
            s1 += __shfl_xor(s1, off);
            s2 += __shfl_xor(s2, off);
        }
        float mu = s1 * (1.0f / EMB);
        float var = s2 * (1.0f / EMB) - mu * mu;
        if (v2)
            out[(size_t)node * EMB + lane] =
                (hv - mu) * rsqrtf(var + LN_EPS) * gamma[lane] + beta[lane];
    }
}

extern "C" void kernel_launch(void* const* d_in, const int* in_sizes, int n_in,
                              void* d_out, int out_size, void* d_ws, size_t ws_size,
                              hipStream_t stream) {
    const float* x        = (const float*)d_in[0];
    const int*   ei       = (const int*)d_in[1];
    const float* edge_attr= (const float*)d_in[2];
    const float* W        = (const float*)d_in[3];
    const float* W_edge   = (const float*)d_in[4];
    const float* att_src  = (const float*)d_in[5];
    const float* att_dst  = (const float*)d_in[6];
    const float* att_edge = (const float*)d_in[7];
    const float* bias     = (const float*)d_in[8];
    const float* Wp       = (const float*)d_in[9];
    const float* bp       = (const float*)d_in[10];
    const float* gamma    = (const float*)d_in[11];
    const float* beta     = (const float*)d_in[12];
    float* out = (float*)d_out;

    int n = in_sizes[0] / EMB;
    int E = in_sizes[1] / 2;
    int nb = (n + 255) / 256;

    float* ws = (float*)d_ws;
    float* a_src       = ws; ws += (size_t)n * HEADS;
    float* a_dst       = ws; ws += (size_t)n * HEADS;
    float* we_att      = ws; ws += EDGE_DIM * HEADS;
    unsigned char* xwf8 = (unsigned char*)ws; ws += (size_t)n * HC / 4;   // 1B/elem
    uint4* recp        = (uint4*)ws; ws += (size_t)E * 4;    // 16B/edge
    unsigned short* WpT = (unsigned short*)ws; ws += HC * EMB / 2;
    unsigned short* WxT = (unsigned short*)ws; ws += NCOLS * EMB / 2;
    int* iw = (int*)ws;
    int* cnt       = iw; iw += n;
    int* rank      = iw; iw += E;
    int* row_start = iw; iw += n;
    int* tmp       = iw; iw += n;
    int* bsum      = iw; iw += 256;

    const int tb = 256;
    hipLaunchKernelGGL(k_prep, dim3((n + tb - 1) / tb), dim3(tb), 0, stream,
                       W_edge, att_edge, we_att, Wp, WpT, W, att_src, att_dst, WxT, cnt, n);
    hipLaunchKernelGGL(k_xw_mfma, dim3((n + 15) / 16), dim3(tb), 0, stream,
                       x, WxT, xwf8, a_src, a_dst, n, ei, cnt, rank, E);
    hipLaunchKernelGGL(k_scan1, dim3(nb), dim3(tb), 0, stream, cnt, tmp, bsum, n);
    hipLaunchKernelGGL(k_scan2, dim3(1), dim3(tb), 0, stream, bsum, nb);
    hipLaunchKernelGGL(k_scan3, dim3(nb), dim3(tb), 0, stream, tmp, cnt, bsum, row_start, n);
    hipLaunchKernelGGL(k_scatter, dim3((E + tb - 1) / tb), dim3(tb), 0, stream,
                       ei, edge_attr, we_att, a_src, a_dst, row_start, rank, recp, E);
    hipLaunchKernelGGL(k_gather_out, dim3((n + NPB - 1) / NPB), dim3(tb), 0, stream,
                       row_start, cnt, recp, a_src, a_dst, xwf8, x, bias, WpT, bp,
                       gamma, beta, out, n);
}

// Round 15
// 152.865 us; speedup vs baseline: 2.8103x; 1.0554x over previous
//
#include <hip/hip_runtime.h>
#include <hip/hip_bf16.h>
#include <hip/hip_fp8.h>
#include <math.h>

#define EMB 64
#define HEADS 4
#define HC 256
#define EDGE_DIM 16
#define NEG_SLOPE 0.2f
#define LN_EPS 1e-5f
#define NCOLS 272   // 256 xw cols + 4 a_src + 4 a_dst + 8 pad
#define CAP 512     // records staged in LDS per chunk
#define NPB 16      // nodes per block (4 per wave)

typedef __attribute__((ext_vector_type(8))) short short8;
typedef __attribute__((ext_vector_type(4))) float f32x4;
typedef __attribute__((ext_vector_type(2))) float f32x2;

__device__ __forceinline__ float bflo(unsigned int u) { return __uint_as_float(u << 16); }
__device__ __forceinline__ float bfhi(unsigned int u) { return __uint_as_float(u & 0xffff0000u); }
__device__ __forceinline__ unsigned short bfb(float f) {
    __hip_bfloat16 h = __float2bfloat16(f);
    return *(unsigned short*)&h;
}
__device__ __forceinline__ unsigned int pack_bf2(float a, float b) {
    return (unsigned int)bfb(a) | ((unsigned int)bfb(b) << 16);
}
__device__ __forceinline__ unsigned char ftofp8(float f) {
    __hip_fp8_e4m3 t(f); return (unsigned char)t.__x;
}

// prep: zero cnt; we_att; WpT[64][256] bf16 (transposed Wp); WxT[272][64] bf16
__global__ void k_prep(const float* __restrict__ W_edge, const float* __restrict__ att_edge,
                       float* __restrict__ we_att, const float* __restrict__ Wp,
                       unsigned short* __restrict__ WpT, const float* __restrict__ W,
                       const float* __restrict__ att_src, const float* __restrict__ att_dst,
                       unsigned short* __restrict__ WxT, int* __restrict__ cnt, int n) {
    int i = blockIdx.x * blockDim.x + threadIdx.x;
    if (i < n) cnt[i] = 0;
    if (i < EDGE_DIM * HEADS) {
        int d = i >> 2, h = i & 3;
        float acc = 0.0f;
#pragma unroll
        for (int c = 0; c < EMB; ++c)
            acc += W_edge[d * HC + h * EMB + c] * att_edge[h * EMB + c];
        we_att[d * HEADS + h] = acc;
    }
    if (i < HC * EMB) {
        int k = i >> 8, jj = i & 255;              // WpT[k][jj] = Wp[jj][k]
        WpT[i] = bfb(Wp[jj * EMB + k]);
    }
    if (i < NCOLS * EMB) {
        int c = i >> 6, k = i & 63;
        float v = 0.0f;
        if (c < HC) {
            v = W[k * HC + c];
        } else if (c < HC + 4) {
            int h = c - HC;
            float s = 0.0f;
#pragma unroll
            for (int j = 0; j < EMB; ++j) s += W[k * HC + h * EMB + j] * att_src[h * EMB + j];
            v = s;
        } else if (c < HC + 8) {
            int h = c - HC - 4;
            float s = 0.0f;
#pragma unroll
            for (int j = 0; j < EMB; ++j) s += W[k * HC + h * EMB + j] * att_dst[h * EMB + j];
            v = s;
        }
        WxT[i] = bfb(v);
    }
}

// ---- MFMA GEMM: [xw(fp8) | a_src | a_dst] = x @ Wx ; 16 nodes/block, 4 waves ----
// fused tail: dst-histogram rank atomic (one edge per thread, grid-stride)
__global__ void __launch_bounds__(256)
k_xw_mfma(const float* __restrict__ x, const unsigned short* __restrict__ WxT,
          unsigned char* __restrict__ xwf8, float* __restrict__ a_src,
          float* __restrict__ a_dst, int n,
          const int* __restrict__ ei, int* __restrict__ cnt,
          int* __restrict__ rank, int E) {
    int tid = threadIdx.x, lane = tid & 63, wv = tid >> 6;
    int g = lane >> 4, r16 = lane & 15;
    int mbase = blockIdx.x * 16;
    int row = mbase + r16;
    if (row >= n) row = n - 1;

    const float* xr = x + (size_t)row * EMB;
    short8 A[2];
#pragma unroll
    for (int kk = 0; kk < 2; ++kk) {
        float4 f0 = *(const float4*)(xr + kk * 32 + 8 * g);
        float4 f1 = *(const float4*)(xr + kk * 32 + 8 * g + 4);
        short8 a;
        a[0] = (short)bfb(f0.x); a[1] = (short)bfb(f0.y);
        a[2] = (short)bfb(f0.z); a[3] = (short)bfb(f0.w);
        a[4] = (short)bfb(f1.x); a[5] = (short)bfb(f1.y);
        a[6] = (short)bfb(f1.z); a[7] = (short)bfb(f1.w);
        A[kk] = a;
    }

    for (int t = wv; t <= 16; t += 4) {
        int col = t * 16 + r16;
        const unsigned short* bp = WxT + (size_t)col * EMB + 8 * g;
        short8 B0 = *(const short8*)(bp);
        short8 B1 = *(const short8*)(bp + 32);
        f32x4 acc = {0.f, 0.f, 0.f, 0.f};
        acc = __builtin_amdgcn_mfma_f32_16x16x32_bf16(A[0], B0, acc, 0, 0, 0);
        acc = __builtin_amdgcn_mfma_f32_16x16x32_bf16(A[1], B1, acc, 0, 0, 0);
        if (t < 16) {
#pragma unroll
            for (int r = 0; r < 4; ++r) {
                int node = mbase + 4 * g + r;
                if (node < n) xwf8[(size_t)node * HC + col] = ftofp8(acc[r]);
            }
        } else {
#pragma unroll
            for (int r = 0; r < 4; ++r) {
                int node = mbase + 4 * g + r;
                if (node < n) {
                    if (r16 < 4) a_src[node * HEADS + r16] = acc[r];
                    else if (r16 < 8) a_dst[node * HEADS + r16 - 4] = acc[r];
                }
            }
        }
    }

    // fused histogram: rank of each edge within its dst bucket
    int stride = gridDim.x * blockDim.x;
    for (int e = blockIdx.x * blockDim.x + tid; e < E; e += stride)
        rank[e] = atomicAdd(&cnt[ei[E + e]], 1);
}

// ---------------- 3-dispatch exclusive scan over cnt[n] ----------------
__global__ void k_scan1(const int* __restrict__ cnt, int* __restrict__ tmp,
                        int* __restrict__ bsum, int n) {
    __shared__ int s[256];
    int i = blockIdx.x * 256 + threadIdx.x;
    int v = (i < n) ? cnt[i] : 0;
    s[threadIdx.x] = v;
    __syncthreads();
    for (int off = 1; off < 256; off <<= 1) {
        int t = (threadIdx.x >= off) ? s[threadIdx.x - off] : 0;
        __syncthreads();
        s[threadIdx.x] += t;
        __syncthreads();
    }
    if (i < n) tmp[i] = s[threadIdx.x];
    if (threadIdx.x == 255) bsum[blockIdx.x] = s[255];
}

__global__ void k_scan2(int* __restrict__ bsum, int nb) {
    __shared__ int s[256];
    int v = (threadIdx.x < nb) ? bsum[threadIdx.x] : 0;
    s[threadIdx.x] = v;
    __syncthreads();
    for (int off = 1; off < 256; off <<= 1) {
        int t = (threadIdx.x >= off) ? s[threadIdx.x - off] : 0;
        __syncthreads();
        s[threadIdx.x] += t;
        __syncthreads();
    }
    if (threadIdx.x < nb) bsum[threadIdx.x] = s[threadIdx.x] - v; // exclusive
}

__global__ void k_scan3(const int* __restrict__ tmp, const int* __restrict__ cnt,
                        const int* __restrict__ bsum, int* __restrict__ row_start, int n) {
    int i = blockIdx.x * 256 + threadIdx.x;
    if (i < n) row_start[i] = tmp[i] - cnt[i] + bsum[blockIdx.x];
}

// ---- scatter: alpha math + 16B CSR record write (no atomics) ----
// record = { ea01.bf16x2, ea23.bf16x2, src.u32, ae.int8x4 (scale 1/32) }
__global__ void k_scatter(const int* __restrict__ ei, const float* __restrict__ edge_attr,
                          const float* __restrict__ we_att, const float* __restrict__ a_src,
                          const float* __restrict__ a_dst, const int* __restrict__ row_start,
                          const int* __restrict__ rank, uint4* __restrict__ recp, int E) {
    __shared__ float wa[EDGE_DIM * HEADS];
    if (threadIdx.x < EDGE_DIM * HEADS) wa[threadIdx.x] = we_att[threadIdx.x];
    __syncthreads();
    int e = blockIdx.x * blockDim.x + threadIdx.x;
    if (e >= E) return;
    int s = ei[e], d = ei[E + e];
    const float4* ea4 = (const float4*)(edge_attr + (size_t)e * EDGE_DIM);
    float ae[HEADS] = {0.f, 0.f, 0.f, 0.f};
#pragma unroll
    for (int q = 0; q < 4; ++q) {
        float4 v4 = ea4[q];
        const float* vp = (const float*)&v4;
#pragma unroll
        for (int r = 0; r < 4; ++r) {
            float v = vp[r];
            int dd = q * 4 + r;
#pragma unroll
            for (int h = 0; h < HEADS; ++h) ae[h] += v * wa[dd * HEADS + h];
        }
    }
    float4 as4 = *(const float4*)(a_src + (size_t)s * HEADS);
    float4 ad4 = *(const float4*)(a_dst + (size_t)d * HEADS);
    const float* asp = (const float*)&as4;
    const float* adp = (const float*)&ad4;
    float ea[HEADS];
    unsigned int aeq = 0;
#pragma unroll
    for (int h = 0; h < HEADS; ++h) {
        float al = asp[h] + adp[h] + ae[h];
        al = al >= 0.0f ? al : NEG_SLOPE * al;
        ea[h] = __expf(al);          // no max-subtraction needed: |al| < ~8
        int q = __float2int_rn(ae[h] * 32.0f);
        q = max(-127, min(127, q));
        aeq |= ((unsigned int)(q & 0xff)) << (8 * h);
    }
    int pos = row_start[d] + rank[e];
    uint4 w;
    w.x = pack_bf2(ea[0], ea[1]);
    w.y = pack_bf2(ea[2], ea[3]);
    w.z = (unsigned int)s;
    w.w = aeq;
    recp[pos] = w;
}

// two-phase gather batch: issue D independent row loads, then decode+accumulate
template<int D>
__device__ __forceinline__ void gather_batch(
    const uint4* recs, int o, int j, const unsigned char* xwf8, int lane,
    int h4, bool hodd, int sh1,
    float& acc0, float& acc1, float& acc2, float& acc3, float& dn, float& aeS) {
    int sv[D];
#pragma unroll
    for (int u = 0; u < D; ++u) sv[u] = (int)recs[o + j + u].z;
    unsigned int rv[D];
#pragma unroll
    for (int u = 0; u < D; ++u)
        rv[u] = *(const unsigned int*)(xwf8 + (size_t)sv[u] * HC + (lane << 2));
#pragma unroll
    for (int u = 0; u < D; ++u) {
        uint4 W = recs[o + j + u];
        unsigned sel = (h4 & 2) ? W.y : W.x;
        float a = hodd ? bfhi(sel) : bflo(sel);
        aeS += (float)((int)(W.w << sh1) >> 24);
        dn += a;
        f32x2 lo2 = __builtin_amdgcn_cvt_pk_f32_fp8((int)rv[u], false);
        f32x2 hi2 = __builtin_amdgcn_cvt_pk_f32_fp8((int)rv[u], true);
        acc0 += a * lo2.x; acc1 += a * lo2.y;
        acc2 += a * hi2.x; acc3 += a * hi2.y;
    }
}

// process one node's record sub-range (batch-8 ladder; lower VGPR than batch-16)
__device__ __forceinline__ void node_range(
    const uint4* recs, int o, int c, const unsigned char* xwf8, int lane,
    int h4, bool hodd, int sh1,
    float& acc0, float& acc1, float& acc2, float& acc3, float& dn, float& aeS) {
    int j = 0;
    for (; j + 8 <= c; j += 8)
        gather_batch<8>(recs, o, j, xwf8, lane, h4, hodd, sh1, acc0, acc1, acc2, acc3, dn, aeS);
    if (j + 4 <= c) {
        gather_batch<4>(recs, o, j, xwf8, lane, h4, hodd, sh1, acc0, acc1, acc2, acc3, dn, aeS);
        j += 4;
    }
    for (; j < c; ++j)
        gather_batch<1>(recs, o, j, xwf8, lane, h4, hodd, sh1, acc0, acc1, acc2, acc3, dn, aeS);
}

// ------- fused gather + softmax + aggregate + MFMA proj + LN -------
// 256 threads: 16 nodes/block, each wave owns 4 contiguous nodes.
// LDS union: recs (gather phase) overlaps gbf+pC (projection phase).
#define LDS_BYTES (NPB * 272 * 2 + NPB * 66 * 4)   // 8704 + 4224 = 12928
__global__ void __launch_bounds__(256)
k_gather_out(const int* __restrict__ row_start, const int* __restrict__ cnt,
             const uint4* __restrict__ recp,
             const float* __restrict__ a_src, const float* __restrict__ a_dst,
             const unsigned char* __restrict__ xwf8, const float* __restrict__ x,
             const float* __restrict__ bias, const unsigned short* __restrict__ WpT,
             const float* __restrict__ bp, const float* __restrict__ gamma,
             const float* __restrict__ beta, float* __restrict__ out, int n) {
    int tid = threadIdx.x, lane = tid & 63, wv = tid >> 6;
    int h4 = lane >> 4;
    bool hodd = (h4 & 1);
    int sh1 = (3 - h4) * 8;

    __shared__ __align__(16) unsigned char ldsbuf[LDS_BYTES];
    uint4* recs = (uint4*)ldsbuf;                                        // [CAP] (8 KB)
    unsigned short (*gbf)[272] = (unsigned short (*)[272])ldsbuf;        // [NPB][272]
    float (*pC)[66] = (float (*)[66])(ldsbuf + NPB * 272 * 2);           // [NPB][66]

    int first = blockIdx.x * NPB;
    int last = min(first + NPB, n) - 1;
    int rs0 = row_start[first];
    int total = row_start[last] + cnt[last] - rs0;

    // this wave's 4 nodes (contiguous)
    int nd[4], dgq[4], mLo[4], mHi[4];
#pragma unroll
    for (int q = 0; q < 4; ++q) {
        int node = first + wv * 4 + q;
        bool v = node < n;
        int nc = v ? node : n - 1;
        nd[q] = nc;
        dgq[q] = v ? cnt[nc] : 0;
        mLo[q] = row_start[nc] - rs0;
        mHi[q] = mLo[q] + dgq[q];
    }

    float a00 = 0.f, a01 = 0.f, a02 = 0.f, a03 = 0.f, dn0 = 0.f, ae0 = 0.f;
    float a10 = 0.f, a11 = 0.f, a12 = 0.f, a13 = 0.f, dn1 = 0.f, ae1 = 0.f;
    float a20 = 0.f, a21 = 0.f, a22 = 0.f, a23 = 0.f, dn2 = 0.f, ae2 = 0.f;
    float a30 = 0.f, a31 = 0.f, a32 = 0.f, a33 = 0.f, dn3 = 0.f, ae3 = 0.f;

    for (int base = 0; base < total; base += CAP) {
        int cend = min(total, base + CAP);
        if (base) __syncthreads();
        for (int idx = base + tid; idx < cend; idx += 256)
            recs[idx - base] = recp[rs0 + idx];
        __syncthreads();
        {
            int lo = max(mLo[0], base), hi = min(mHi[0], cend);
            if (hi > lo) node_range(recs, lo - base, hi - lo, xwf8, lane, h4, hodd, sh1,
                                    a00, a01, a02, a03, dn0, ae0);
        }
        {
            int lo = max(mLo[1], base), hi = min(mHi[1], cend);
            if (hi > lo) node_range(recs, lo - base, hi - lo, xwf8, lane, h4, hodd, sh1,
                                    a10, a11, a12, a13, dn1, ae1);
        }
        {
            int lo = max(mLo[2], base), hi = min(mHi[2], cend);
            if (hi > lo) node_range(recs, lo - base, hi - lo, xwf8, lane, h4, hodd, sh1,
                                    a20, a21, a22, a23, dn2, ae2);
        }
        {
            int lo = max(mLo[3], base), hi = min(mHi[3], cend);
            if (hi > lo) node_range(recs, lo - base, hi - lo, xwf8, lane, h4, hodd, sh1,
                                    a30, a31, a32, a33, dn3, ae3);
        }
    }
    __syncthreads();   // recs lifetime ends; gbf/pC aliases become live

    // finalize each of the wave's 4 nodes: self-loop + normalize + bias -> bf16 g
    float4 bv = *(const float4*)(bias + (lane << 2));
#pragma unroll
    for (int q = 0; q < 4; ++q) {
        float A0 = (q == 0) ? a00 : (q == 1) ? a10 : (q == 2) ? a20 : a30;
        float A1 = (q == 0) ? a01 : (q == 1) ? a11 : (q == 2) ? a21 : a31;
        float A2 = (q == 0) ? a02 : (q == 1) ? a12 : (q == 2) ? a22 : a32;
        float A3 = (q == 0) ? a03 : (q == 1) ? a13 : (q == 2) ? a23 : a33;
        float DN = (q == 0) ? dn0 : (q == 1) ? dn1 : (q == 2) ? dn2 : dn3;
        float AE = (q == 0) ? ae0 : (q == 1) ? ae1 : (q == 2) ? ae2 : ae3;
        int nc = nd[q];
        float as = a_src[nc * HEADS + h4];
        float ad = a_dst[nc * HEADS + h4];
        unsigned int sr8 = *(const unsigned int*)(xwf8 + (size_t)nc * HC + (lane << 2));
        float cf = fmaxf((float)dgq[q], 1.0f);
        float al = as + ad + (AE * (1.0f / 32.0f)) / cf;
        al = al >= 0.f ? al : NEG_SLOPE * al;
        float el = __expf(al);
        float inv = 1.0f / (DN + el);
        f32x2 slo = __builtin_amdgcn_cvt_pk_f32_fp8((int)sr8, false);
        f32x2 shi = __builtin_amdgcn_cvt_pk_f32_fp8((int)sr8, true);
        ushort4 gv;
        gv.x = bfb((A0 + el * slo.x) * inv + bv.x);
        gv.y = bfb((A1 + el * slo.y) * inv + bv.y);
        gv.z = bfb((A2 + el * shi.x) * inv + bv.z);
        gv.w = bfb((A3 + el * shi.y) * inv + bv.w);
        *(ushort4*)&gbf[wv * 4 + q][lane << 2] = gv;
    }
    __syncthreads();

    // MFMA projection: full M=16. wave wv computes col tile wv of g(16x256) @ Wp(256x64)
    {
        int g = lane >> 4, r16 = lane & 15;
        const unsigned short* wp = WpT + (size_t)(wv * 16 + r16) * HC + 8 * g;
        const unsigned short* ga = &gbf[r16][8 * g];
        f32x4 pacc = {0.f, 0.f, 0.f, 0.f};
#pragma unroll
        for (int kk = 0; kk < 8; ++kk) {
            short8 Af = *(const short8*)(ga + kk * 32);
            short8 Bf = *(const short8*)(wp + kk * 32);
            pacc = __builtin_amdgcn_mfma_f32_16x16x32_bf16(Af, Bf, pacc, 0, 0, 0);
        }
#pragma unroll
        for (int m = 0; m < 4; ++m) pC[4 * g + m][wv * 16 + r16] = pacc[m];
    }
    __syncthreads();

    // epilogue: 4 passes; pass p -> local node wv + 4p; lane = channel
#pragma unroll
    for (int p = 0; p < 4; ++p) {
        int local = wv + 4 * p;
        int node = first + local;
        bool v2 = node < n;
        float pv = pC[local][lane] + bp[lane];
        float elv = pv > 0.f ? pv : expm1f(pv);
        float xv = v2 ? x[(size_t)node * EMB + lane] : 0.f;
        float hv = xv + elv;
        float s1 = hv, s2 = hv * hv;
        for (int off = 32; off > 0; off >>= 1) {
            s1 += __shfl_xor(s1, off);
            s2 += __shfl_xor(s2, off);
        }
        float mu = s1 * (1.0f / EMB);
        float var = s2 * (1.0f / EMB) - mu * mu;
        if (v2)
            out[(size_t)node * EMB + lane] =
                (hv - mu) * rsqrtf(var + LN_EPS) * gamma[lane] + beta[lane];
    }
}

extern "C" void kernel_launch(void* const* d_in, const int* in_sizes, int n_in,
                              void* d_out, int out_size, void* d_ws, size_t ws_size,
                              hipStream_t stream) {
    const float* x        = (const float*)d_in[0];
    const int*   ei       = (const int*)d_in[1];
    const float* edge_attr= (const float*)d_in[2];
    const float* W        = (const float*)d_in[3];
    const float* W_edge   = (const float*)d_in[4];
    const float* att_src  = (const float*)d_in[5];
    const float* att_dst  = (const float*)d_in[6];
    const float* att_edge = (const float*)d_in[7];
    const float* bias     = (const float*)d_in[8];
    const float* Wp       = (const float*)d_in[9];
    const float* bp       = (const float*)d_in[10];
    const float* gamma    = (const float*)d_in[11];
    const float* beta     = (const float*)d_in[12];
    float* out = (float*)d_out;

    int n = in_sizes[0] / EMB;
    int E = in_sizes[1] / 2;
    int nb = (n + 255) / 256;

    float* ws = (float*)d_ws;
    float* a_src       = ws; ws += (size_t)n * HEADS;
    float* a_dst       = ws; ws += (size_t)n * HEADS;
    float* we_att      = ws; ws += EDGE_DIM * HEADS;
    unsigned char* xwf8 = (unsigned char*)ws; ws += (size_t)n * HC / 4;   // 1B/elem
    uint4* recp        = (uint4*)ws; ws += (size_t)E * 4;    // 16B/edge
    unsigned short* WpT = (unsigned short*)ws; ws += HC * EMB / 2;
    unsigned short* WxT = (unsigned short*)ws; ws += NCOLS * EMB / 2;
    int* iw = (int*)ws;
    int* cnt       = iw; iw += n;
    int* rank      = iw; iw += E;
    int* row_start = iw; iw += n;
    int* tmp       = iw; iw += n;
    int* bsum      = iw; iw += 256;

    const int tb = 256;
    hipLaunchKernelGGL(k_prep, dim3((n + tb - 1) / tb), dim3(tb), 0, stream,
                       W_edge, att_edge, we_att, Wp, WpT, W, att_src, att_dst, WxT, cnt, n);
    hipLaunchKernelGGL(k_xw_mfma, dim3((n + 15) / 16), dim3(tb), 0, stream,
                       x, WxT, xwf8, a_src, a_dst, n, ei, cnt, rank, E);
    hipLaunchKernelGGL(k_scan1, dim3(nb), dim3(tb), 0, stream, cnt, tmp, bsum, n);
    hipLaunchKernelGGL(k_scan2, dim3(1), dim3(tb), 0, stream, bsum, nb);
    hipLaunchKernelGGL(k_scan3, dim3(nb), dim3(tb), 0, stream, tmp, cnt, bsum, row_start, n);
    hipLaunchKernelGGL(k_scatter, dim3((E + tb - 1) / tb), dim3(tb), 0, stream,
                       ei, edge_attr, we_att, a_src, a_dst, row_start, rank, recp, E);
    hipLaunchKernelGGL(k_gather_out, dim3((n + NPB - 1) / NPB), dim3(tb), 0, stream,
                       row_start, cnt, recp, a_src, a_dst, xwf8, x, bias, WpT, bp,
                       gamma, beta, out, n);
}